// Round 2
// baseline (2690.047 us; speedup 1.0000x reference)
//
#include <hip/hip_runtime.h>
#include <math.h>

#define N_NODES 4096
#define N_EDGES 262144
#define K_DIM 256

// ---------------------------------------------------------------------------
// Graph preprocessing: degree, dinv, CSR by destination (col)
// ---------------------------------------------------------------------------
__global__ void init_deg_cnt(float* deg, int* cnt) {
    int i = blockIdx.x * blockDim.x + threadIdx.x;
    if (i < N_NODES) { deg[i] = 1.0f; cnt[i] = 0; }  // 1.0 = self-loop weight
}

__global__ void deg_accum(const int* __restrict__ col, const float* __restrict__ ew,
                          float* deg, int* cnt) {
    for (int e = blockIdx.x * blockDim.x + threadIdx.x; e < N_EDGES;
         e += gridDim.x * blockDim.x) {
        int c = col[e];
        atomicAdd(&deg[c], ew[e]);
        atomicAdd(&cnt[c], 1);
    }
}

__global__ void finalize_dinv(float* deg) {
    int i = blockIdx.x * blockDim.x + threadIdx.x;
    if (i < N_NODES) { float d = deg[i]; deg[i] = d > 0.f ? rsqrtf(d) : 0.f; }
}

// 1 block, 1024 threads: exclusive prefix over 4096 counts (Hillis-Steele)
__global__ __launch_bounds__(1024) void scan_offsets(const int* __restrict__ cnt,
                                                     int* off, int* fill) {
    __shared__ int s[1024];
    int tid = threadIdx.x;
    int c0 = cnt[tid * 4 + 0], c1 = cnt[tid * 4 + 1];
    int c2 = cnt[tid * 4 + 2], c3 = cnt[tid * 4 + 3];
    int lsum = c0 + c1 + c2 + c3;
    s[tid] = lsum;
    __syncthreads();
    for (int d = 1; d < 1024; d <<= 1) {
        int v = (tid >= d) ? s[tid - d] : 0;
        __syncthreads();
        s[tid] += v;
        __syncthreads();
    }
    int incl = s[tid];
    int base = incl - lsum;
    int o0 = base, o1 = base + c0, o2 = base + c0 + c1, o3 = base + c0 + c1 + c2;
    off[tid * 4 + 0] = o0;  fill[tid * 4 + 0] = o0;
    off[tid * 4 + 1] = o1;  fill[tid * 4 + 1] = o1;
    off[tid * 4 + 2] = o2;  fill[tid * 4 + 2] = o2;
    off[tid * 4 + 3] = o3;  fill[tid * 4 + 3] = o3;
    if (tid == 1023) off[4096] = incl;
}

__global__ void scatter_edges(const int* __restrict__ row, const int* __restrict__ col,
                              const float* __restrict__ ew, const float* __restrict__ dinv,
                              int* fill, int* srow, float* snorm) {
    for (int e = blockIdx.x * blockDim.x + threadIdx.x; e < N_EDGES;
         e += gridDim.x * blockDim.x) {
        int r = row[e], c = col[e];
        int p = atomicAdd(&fill[c], 1);
        srow[p] = r;
        snorm[p] = dinv[r] * ew[e] * dinv[c];
    }
}

// ---------------------------------------------------------------------------
// fp32 GEMM: C[N x P] = X[N x 256] @ B + (bias) (+relu)
//   BTRANS=false: B = W [256][P] row-major (GCN weights)
//   BTRANS=true : B[k][j] = W[j*256+k], W is [P][256] row-major (attn proj)
// 64x64 tile, 256 threads, 4x4 per thread, K-chunk 16
// ---------------------------------------------------------------------------
template <bool BTRANS, bool BIAS, int ACT>
__global__ __launch_bounds__(256) void gemm256(const float* __restrict__ X,
                                               const float* __restrict__ W,
                                               const float* __restrict__ bias,
                                               float* __restrict__ C, int P) {
    __shared__ float As[64][17];
    __shared__ float Bs[16][65];
    int tx = threadIdx.x, ty = threadIdx.y;
    int tid = ty * 16 + tx;
    int brow = blockIdx.y * 64, bcol = blockIdx.x * 64;
    float acc[4][4] = {};
    for (int k0 = 0; k0 < K_DIM; k0 += 16) {
        {
            int r = tid >> 4, kk = tid & 15;
#pragma unroll
            for (int q = 0; q < 4; q++)
                As[r + q * 16][kk] = X[(brow + r + q * 16) * K_DIM + k0 + kk];
        }
        if (!BTRANS) {
            int c = tid & 63, kk = tid >> 6;
#pragma unroll
            for (int q = 0; q < 4; q++)
                Bs[kk + q * 4][c] = W[(k0 + kk + q * 4) * P + bcol + c];
        } else {
            int c = tid >> 4, kk = tid & 15;
#pragma unroll
            for (int q = 0; q < 4; q++)
                Bs[kk][c + q * 16] = W[(bcol + c + q * 16) * K_DIM + k0 + kk];
        }
        __syncthreads();
#pragma unroll
        for (int kk = 0; kk < 16; kk++) {
            float a[4], b[4];
#pragma unroll
            for (int i = 0; i < 4; i++) a[i] = As[ty * 4 + i][kk];
#pragma unroll
            for (int j = 0; j < 4; j++) b[j] = Bs[kk][tx * 4 + j];
#pragma unroll
            for (int i = 0; i < 4; i++)
#pragma unroll
                for (int j = 0; j < 4; j++) acc[i][j] += a[i] * b[j];
        }
        __syncthreads();
    }
#pragma unroll
    for (int i = 0; i < 4; i++) {
        int r = brow + ty * 4 + i;
#pragma unroll
        for (int j = 0; j < 4; j++) {
            int c = bcol + tx * 4 + j;
            float v = acc[i][j];
            if (BIAS) v += bias[c];
            if (ACT == 1) v = fmaxf(v, 0.f);
            C[r * P + c] = v;
        }
    }
}

// ---------------------------------------------------------------------------
// GCN aggregation: out[i] = sum_in-edges norm*H[row] + dinv[i]^2*H[i] + bias
// One block per node; edge metadata broadcast via LDS chunks.
// ACT: 0 none, 2 sigmoid
// ---------------------------------------------------------------------------
template <int P, int ACT>
__global__ void gcn_agg(const float* __restrict__ H, const int* __restrict__ off,
                        const int* __restrict__ srow, const float* __restrict__ snorm,
                        const float* __restrict__ dinv, const float* __restrict__ bias,
                        float* __restrict__ out) {
    __shared__ int sr[256];
    __shared__ float sw[256];
    int i = blockIdx.x, tid = threadIdx.x;
    float di = dinv[i];
    float acc = di * di * H[i * P + tid];
    int beg = off[i], end = off[i + 1];
    for (int base = beg; base < end; base += P) {
        int n = min(P, end - base);
        __syncthreads();
        if (tid < n) { sr[tid] = srow[base + tid]; sw[tid] = snorm[base + tid]; }
        __syncthreads();
        for (int j = 0; j < n; j++) acc += sw[j] * H[sr[j] * P + tid];
    }
    float v = acc + bias[tid];
    if (ACT == 2) v = 1.f / (1.f + __expf(-v));
    out[i * P + tid] = v;
}

// ---------------------------------------------------------------------------
// Flash-style fp32 attention. qkv: [N][768] (q|k|v). att: [N][256].
// grid (qtile=N/16, head=4), 256 threads: (q=tid>>4) x (t=tid&15), 4 dims each.
// ---------------------------------------------------------------------------
__global__ __launch_bounds__(256) void attn_fp32(const float* __restrict__ qkv,
                                                 float* __restrict__ att) {
    __shared__ float Qs[16][65];
    __shared__ float Ks[64][65];
    __shared__ float Vs[64][65];
    __shared__ float Ps[16][65];
    int tid = threadIdx.x;
    int q = tid >> 4, t = tid & 15;
    int head = blockIdx.y;
    int q0 = blockIdx.x * 16;
    int hq = head * 64, hk = 256 + head * 64, hv = 512 + head * 64;

    for (int idx = tid; idx < 16 * 64; idx += 256) {
        int r = idx >> 6, c = idx & 63;
        Qs[r][c] = qkv[(q0 + r) * 768 + hq + c] * 0.125f;  // 1/sqrt(64)
    }
    float m = -1e30f, l = 0.f;
    float acc[4] = {0.f, 0.f, 0.f, 0.f};

    for (int kt = 0; kt < 64; kt++) {
        __syncthreads();
        for (int idx = tid; idx < 64 * 64; idx += 256) {
            int r = idx >> 6, c = idx & 63;
            int rowb = (kt * 64 + r) * 768;
            Ks[r][c] = qkv[rowb + hk + c];
            Vs[r][c] = qkv[rowb + hv + c];
        }
        __syncthreads();

        float s[4] = {0.f, 0.f, 0.f, 0.f};
#pragma unroll 8
        for (int k = 0; k < 64; k++) {
            float qv = Qs[q][k];
#pragma unroll
            for (int j = 0; j < 4; j++) s[j] += qv * Ks[t * 4 + j][k];
        }
        float tm = fmaxf(fmaxf(s[0], s[1]), fmaxf(s[2], s[3]));
        for (int d = 1; d < 16; d <<= 1) tm = fmaxf(tm, __shfl_xor(tm, d, 16));
        float mn = fmaxf(m, tm);
        float scale = __expf(m - mn);
        float p[4];
        float ps = 0.f;
#pragma unroll
        for (int j = 0; j < 4; j++) { p[j] = __expf(s[j] - mn); ps += p[j]; }
        for (int d = 1; d < 16; d <<= 1) ps += __shfl_xor(ps, d, 16);
        l = l * scale + ps;
        m = mn;
#pragma unroll
        for (int j = 0; j < 4; j++) { acc[j] *= scale; Ps[q][t * 4 + j] = p[j]; }
        __syncthreads();
#pragma unroll 8
        for (int mm = 0; mm < 64; mm++) {
            float pv = Ps[q][mm];
#pragma unroll
            for (int j = 0; j < 4; j++) acc[j] += pv * Vs[mm][t * 4 + j];
        }
    }
    float linv = 1.f / l;
#pragma unroll
    for (int j = 0; j < 4; j++)
        att[(q0 + q) * 256 + head * 64 + t * 4 + j] = acc[j] * linv;
}

// ---------------------------------------------------------------------------
extern "C" void kernel_launch(void* const* d_in, const int* in_sizes, int n_in,
                              void* d_out, int out_size, void* d_ws, size_t ws_size,
                              hipStream_t stream) {
    const float* x0  = (const float*)d_in[0];
    const int*   eix = (const int*)d_in[1];
    const float* ew  = (const float*)d_in[2];
    const float* W1  = (const float*)d_in[3];
    const float* b1  = (const float*)d_in[4];
    const float* W2  = (const float*)d_in[5];
    const float* b2  = (const float*)d_in[6];
    const float* W3  = (const float*)d_in[7];
    const float* b3  = (const float*)d_in[8];
    const float* ipw = (const float*)d_in[9];
    const float* ipb = (const float*)d_in[10];
    const float* opw = (const float*)d_in[11];
    const float* opb = (const float*)d_in[12];
    float* out = (float*)d_out;

    char* ws = (char*)d_ws;
    size_t o = 0;
    auto alloc = [&](size_t bytes) -> void* {
        void* p = ws + o;
        o = (o + bytes + 255) & ~size_t(255);
        return p;
    };
    float* dinv  = (float*)alloc(N_NODES * 4);
    int*   cnt   = (int*)alloc(N_NODES * 4);
    int*   off   = (int*)alloc((N_NODES + 1) * 4);
    int*   fill  = (int*)alloc(N_NODES * 4);
    int*   srow  = (int*)alloc(N_EDGES * 4);
    float* snorm = (float*)alloc(N_EDGES * 4);
    float* H     = (float*)alloc((size_t)N_NODES * 256 * 4);
    float* QKV   = (float*)alloc((size_t)N_NODES * 768 * 4);
    float* XA    = (float*)alloc((size_t)N_NODES * 256 * 4);
    float* XB    = (float*)alloc((size_t)N_NODES * 256 * 4);

    const int* row = eix;
    const int* col = eix + N_EDGES;

    // graph preprocessing (shared by all 3 GCN layers)
    init_deg_cnt<<<16, 256, 0, stream>>>(dinv, cnt);
    deg_accum<<<512, 256, 0, stream>>>(col, ew, dinv, cnt);
    finalize_dinv<<<16, 256, 0, stream>>>(dinv);
    scan_offsets<<<1, 1024, 0, stream>>>(cnt, off, fill);
    scatter_edges<<<512, 256, 0, stream>>>(row, col, ew, dinv, fill, srow, snorm);

    dim3 thr(16, 16);
    // GCN layer 1
    gemm256<false, false, 0><<<dim3(4, 64), thr, 0, stream>>>(x0, W1, nullptr, H, 256);
    gcn_agg<256, 0><<<N_NODES, 256, 0, stream>>>(H, off, srow, snorm, dinv, b1, XA);
    // MHA 1 (+relu)
    gemm256<true, true, 0><<<dim3(12, 64), thr, 0, stream>>>(XA, ipw, ipb, QKV, 768);
    attn_fp32<<<dim3(256, 4), 256, 0, stream>>>(QKV, H);
    gemm256<true, true, 1><<<dim3(4, 64), thr, 0, stream>>>(H, opw, opb, XB, 256);
    // GCN layer 2
    gemm256<false, false, 0><<<dim3(4, 64), thr, 0, stream>>>(XB, W2, nullptr, H, 256);
    gcn_agg<256, 0><<<N_NODES, 256, 0, stream>>>(H, off, srow, snorm, dinv, b2, XA);
    // MHA 2 (+relu)
    gemm256<true, true, 0><<<dim3(12, 64), thr, 0, stream>>>(XA, ipw, ipb, QKV, 768);
    attn_fp32<<<dim3(256, 4), 256, 0, stream>>>(QKV, H);
    gemm256<true, true, 1><<<dim3(4, 64), thr, 0, stream>>>(H, opw, opb, XB, 256);
    // GCN layer 3 (+sigmoid) -> d_out
    gemm256<false, false, 0><<<dim3(2, 64), thr, 0, stream>>>(XB, W3, nullptr, H, 128);
    gcn_agg<128, 2><<<N_NODES, 128, 0, stream>>>(H, off, srow, snorm, dinv, b3, out);
}

// Round 3
// 552.862 us; speedup vs baseline: 4.8657x; 4.8657x over previous
//
#include <hip/hip_runtime.h>
#include <math.h>

#define N_NODES 4096
#define N_EDGES 262144
#define K_DIM 256

typedef __attribute__((ext_vector_type(4))) float f32x4;
typedef __attribute__((ext_vector_type(8))) short s16x8;

__device__ inline unsigned short f2bf(float f) {
    unsigned u = __builtin_bit_cast(unsigned, f);
    u += 0x7FFF + ((u >> 16) & 1);  // RNE
    return (unsigned short)(u >> 16);
}

// ---------------------------------------------------------------------------
// Graph preprocessing: degree, dinv, CSR by destination (col)
// ---------------------------------------------------------------------------
__global__ void init_deg_cnt(float* deg, int* cnt) {
    int i = blockIdx.x * blockDim.x + threadIdx.x;
    if (i < N_NODES) { deg[i] = 1.0f; cnt[i] = 0; }  // 1.0 = self-loop weight
}

__global__ void deg_accum(const int* __restrict__ col, const float* __restrict__ ew,
                          float* deg, int* cnt) {
    for (int e = blockIdx.x * blockDim.x + threadIdx.x; e < N_EDGES;
         e += gridDim.x * blockDim.x) {
        int c = col[e];
        atomicAdd(&deg[c], ew[e]);
        atomicAdd(&cnt[c], 1);
    }
}

__global__ void finalize_dinv(float* deg) {
    int i = blockIdx.x * blockDim.x + threadIdx.x;
    if (i < N_NODES) { float d = deg[i]; deg[i] = d > 0.f ? rsqrtf(d) : 0.f; }
}

__global__ __launch_bounds__(1024) void scan_offsets(const int* __restrict__ cnt,
                                                     int* off, int* fill) {
    __shared__ int s[1024];
    int tid = threadIdx.x;
    int c0 = cnt[tid * 4 + 0], c1 = cnt[tid * 4 + 1];
    int c2 = cnt[tid * 4 + 2], c3 = cnt[tid * 4 + 3];
    int lsum = c0 + c1 + c2 + c3;
    s[tid] = lsum;
    __syncthreads();
    for (int d = 1; d < 1024; d <<= 1) {
        int v = (tid >= d) ? s[tid - d] : 0;
        __syncthreads();
        s[tid] += v;
        __syncthreads();
    }
    int incl = s[tid];
    int base = incl - lsum;
    int o0 = base, o1 = base + c0, o2 = base + c0 + c1, o3 = base + c0 + c1 + c2;
    off[tid * 4 + 0] = o0;  fill[tid * 4 + 0] = o0;
    off[tid * 4 + 1] = o1;  fill[tid * 4 + 1] = o1;
    off[tid * 4 + 2] = o2;  fill[tid * 4 + 2] = o2;
    off[tid * 4 + 3] = o3;  fill[tid * 4 + 3] = o3;
    if (tid == 1023) off[4096] = incl;
}

__global__ void scatter_edges(const int* __restrict__ row, const int* __restrict__ col,
                              const float* __restrict__ ew, const float* __restrict__ dinv,
                              int* fill, int* srow, float* snorm) {
    for (int e = blockIdx.x * blockDim.x + threadIdx.x; e < N_EDGES;
         e += gridDim.x * blockDim.x) {
        int r = row[e], c = col[e];
        int p = atomicAdd(&fill[c], 1);
        srow[p] = r;
        snorm[p] = dinv[r] * ew[e] * dinv[c];
    }
}

// ---------------------------------------------------------------------------
// fp32 GEMM (unchanged this round)
// ---------------------------------------------------------------------------
template <bool BTRANS, bool BIAS, int ACT>
__global__ __launch_bounds__(256) void gemm256(const float* __restrict__ X,
                                               const float* __restrict__ W,
                                               const float* __restrict__ bias,
                                               float* __restrict__ C, int P) {
    __shared__ float As[64][17];
    __shared__ float Bs[16][65];
    int tx = threadIdx.x, ty = threadIdx.y;
    int tid = ty * 16 + tx;
    int brow = blockIdx.y * 64, bcol = blockIdx.x * 64;
    float acc[4][4] = {};
    for (int k0 = 0; k0 < K_DIM; k0 += 16) {
        {
            int r = tid >> 4, kk = tid & 15;
#pragma unroll
            for (int q = 0; q < 4; q++)
                As[r + q * 16][kk] = X[(brow + r + q * 16) * K_DIM + k0 + kk];
        }
        if (!BTRANS) {
            int c = tid & 63, kk = tid >> 6;
#pragma unroll
            for (int q = 0; q < 4; q++)
                Bs[kk + q * 4][c] = W[(k0 + kk + q * 4) * P + bcol + c];
        } else {
            int c = tid >> 4, kk = tid & 15;
#pragma unroll
            for (int q = 0; q < 4; q++)
                Bs[kk][c + q * 16] = W[(bcol + c + q * 16) * K_DIM + k0 + kk];
        }
        __syncthreads();
#pragma unroll
        for (int kk = 0; kk < 16; kk++) {
            float a[4], b[4];
#pragma unroll
            for (int i = 0; i < 4; i++) a[i] = As[ty * 4 + i][kk];
#pragma unroll
            for (int j = 0; j < 4; j++) b[j] = Bs[kk][tx * 4 + j];
#pragma unroll
            for (int i = 0; i < 4; i++)
#pragma unroll
                for (int j = 0; j < 4; j++) acc[i][j] += a[i] * b[j];
        }
        __syncthreads();
    }
#pragma unroll
    for (int i = 0; i < 4; i++) {
        int r = brow + ty * 4 + i;
#pragma unroll
        for (int j = 0; j < 4; j++) {
            int c = bcol + tx * 4 + j;
            float v = acc[i][j];
            if (BIAS) v += bias[c];
            if (ACT == 1) v = fmaxf(v, 0.f);
            C[r * P + c] = v;
        }
    }
}

// ---------------------------------------------------------------------------
// GCN aggregation (unchanged this round)
// ---------------------------------------------------------------------------
template <int P, int ACT>
__global__ void gcn_agg(const float* __restrict__ H, const int* __restrict__ off,
                        const int* __restrict__ srow, const float* __restrict__ snorm,
                        const float* __restrict__ dinv, const float* __restrict__ bias,
                        float* __restrict__ out) {
    __shared__ int sr[256];
    __shared__ float sw[256];
    int i = blockIdx.x, tid = threadIdx.x;
    float di = dinv[i];
    float acc = di * di * H[i * P + tid];
    int beg = off[i], end = off[i + 1];
    for (int base = beg; base < end; base += P) {
        int n = min(P, end - base);
        __syncthreads();
        if (tid < n) { sr[tid] = srow[base + tid]; sw[tid] = snorm[base + tid]; }
        __syncthreads();
        for (int j = 0; j < n; j++) acc += sw[j] * H[sr[j] * P + tid];
    }
    float v = acc + bias[tid];
    if (ACT == 2) v = 1.f / (1.f + __expf(-v));
    out[i * P + tid] = v;
}

// ---------------------------------------------------------------------------
// MHA prep: K -> bf16 [head][n][64]; V -> bf16 transposed [head][d][n]
// grid (64 n-tiles, 4 heads), 256 threads
// ---------------------------------------------------------------------------
__global__ __launch_bounds__(256) void prep_kv(const float* __restrict__ qkv,
                                               unsigned short* __restrict__ Kb,
                                               unsigned short* __restrict__ Vt) {
    __shared__ float vt[64][65];
    int head = blockIdx.y, n0 = blockIdx.x * 64, tid = threadIdx.x;
#pragma unroll
    for (int it = 0; it < 16; ++it) {
        int idx = tid + it * 256;
        int r = idx >> 6, c = idx & 63;
        const float* src = qkv + (size_t)(n0 + r) * 768 + head * 64;
        Kb[(size_t)(head * 4096 + n0 + r) * 64 + c] = f2bf(src[256 + c]);
        vt[c][r] = src[512 + c];
    }
    __syncthreads();
#pragma unroll
    for (int it = 0; it < 16; ++it) {
        int idx = tid + it * 256;
        int d = idx >> 6, c = idx & 63;
        Vt[(size_t)(head * 64 + d) * 4096 + n0 + c] = f2bf(vt[d][c]);
    }
}

// ---------------------------------------------------------------------------
// MFMA flash attention. qkv fp32 [N][768] (Q read directly), Kb/Vt bf16.
// grid (64 q-tiles, 4 heads), 256 threads = 4 waves x 16 q-rows.
// LDS tiles XOR-swizzled: byte ^= (row&7)<<4 within 128B rows (T2).
// ---------------------------------------------------------------------------
#define SWZ(row, colb) (((row) << 7) + ((colb) ^ (((row) & 7) << 4)))

__global__ __launch_bounds__(256) void attn_mfma(const float* __restrict__ qkv,
                                                 const unsigned short* __restrict__ Kb,
                                                 const unsigned short* __restrict__ Vt,
                                                 float* __restrict__ att) {
    __shared__ unsigned short Ks[64 * 64];   // [kr][d] swizzled
    __shared__ unsigned short Vs[64 * 64];   // [d][kr] swizzled (V^T)
    __shared__ unsigned short Ps[4][16 * 64];  // per-wave P [q][kr] swizzled

    int tid = threadIdx.x;
    int wid = tid >> 6, lane = tid & 63, g = lane >> 4, lx = lane & 15;
    int head = blockIdx.y;
    int qw = blockIdx.x * 64 + wid * 16;   // wave's 16 q-rows

    // Q a-frags, pre-scaled by 1/sqrt(64)
    s16x8 qa[2];
    {
        const float* qp = qkv + (size_t)(qw + lx) * 768 + head * 64 + g * 8;
#pragma unroll
        for (int kc = 0; kc < 2; kc++) {
            const float* p = qp + kc * 32;
            s16x8 v;
#pragma unroll
            for (int i = 0; i < 8; i++) v[i] = (short)f2bf(p[i] * 0.125f);
            qa[kc] = v;
        }
    }

    const unsigned short* KbH = Kb + (size_t)head * 4096 * 64;
    const unsigned short* VtH = Vt + (size_t)head * 64 * 4096;

    // staging: 512 chunks of 16B per tile array; thread owns chunks tid, tid+256
    int kr0 = tid >> 3, dc0 = tid & 7;
    int kr1 = (tid + 256) >> 3, dc1 = tid & 7;  // (tid+256)&7 == tid&7
    s16x8 stK[2], stV[2];
    auto issue = [&](int kt) {
        stK[0] = *(const s16x8*)(KbH + (size_t)(kt * 64 + kr0) * 64 + dc0 * 8);
        stK[1] = *(const s16x8*)(KbH + (size_t)(kt * 64 + kr1) * 64 + dc1 * 8);
        stV[0] = *(const s16x8*)(VtH + (size_t)kr0 * 4096 + kt * 64 + dc0 * 8);
        stV[1] = *(const s16x8*)(VtH + (size_t)kr1 * 4096 + kt * 64 + dc1 * 8);
    };
    auto commit = [&]() {
        *(s16x8*)((char*)Ks + SWZ(kr0, dc0 * 16)) = stK[0];
        *(s16x8*)((char*)Ks + SWZ(kr1, dc1 * 16)) = stK[1];
        *(s16x8*)((char*)Vs + SWZ(kr0, dc0 * 16)) = stV[0];
        *(s16x8*)((char*)Vs + SWZ(kr1, dc1 * 16)) = stV[1];
    };

    float mreg[4] = {-1e30f, -1e30f, -1e30f, -1e30f};
    float lreg[4] = {0.f, 0.f, 0.f, 0.f};
    f32x4 o[4];
#pragma unroll
    for (int dt = 0; dt < 4; dt++) o[dt] = f32x4{0.f, 0.f, 0.f, 0.f};

    char* PsW = (char*)Ps + wid * (16 * 64 * 2);

    issue(0);
    commit();
    __syncthreads();

    for (int kt = 0; kt < 64; kt++) {
        // QK^T: S[16q][64kr]
        f32x4 s4[4];
#pragma unroll
        for (int nt = 0; nt < 4; nt++) {
            f32x4 acc = f32x4{0.f, 0.f, 0.f, 0.f};
#pragma unroll
            for (int kc = 0; kc < 2; kc++) {
                s16x8 kb = *(const s16x8*)((char*)Ks + SWZ(nt * 16 + lx, kc * 64 + g * 16));
                acc = __builtin_amdgcn_mfma_f32_16x16x32_bf16(qa[kc], kb, acc, 0, 0, 0);
            }
            s4[nt] = acc;
        }

        // online softmax (rows 4g+r are lane-group-local; reduce over 16 lanes)
        float scl[4];
#pragma unroll
        for (int r = 0; r < 4; r++) {
            float pm = fmaxf(fmaxf(s4[0][r], s4[1][r]), fmaxf(s4[2][r], s4[3][r]));
            pm = fmaxf(pm, __shfl_xor(pm, 1, 16));
            pm = fmaxf(pm, __shfl_xor(pm, 2, 16));
            pm = fmaxf(pm, __shfl_xor(pm, 4, 16));
            pm = fmaxf(pm, __shfl_xor(pm, 8, 16));
            float mn = fmaxf(mreg[r], pm);
            float sc = __expf(mreg[r] - mn);
            float ps = 0.f;
#pragma unroll
            for (int nt = 0; nt < 4; nt++) {
                float p = __expf(s4[nt][r] - mn);
                s4[nt][r] = p;
                ps += p;
            }
            ps += __shfl_xor(ps, 1, 16);
            ps += __shfl_xor(ps, 2, 16);
            ps += __shfl_xor(ps, 4, 16);
            ps += __shfl_xor(ps, 8, 16);
            lreg[r] = lreg[r] * sc + ps;
            mreg[r] = mn;
            scl[r] = sc;
        }
        // write P (bf16) to wave-private LDS
#pragma unroll
        for (int nt = 0; nt < 4; nt++)
#pragma unroll
            for (int r = 0; r < 4; r++)
                *(unsigned short*)(PsW + SWZ(4 * g + r, (nt * 16 + lx) * 2)) =
                    f2bf(s4[nt][r]);
        // rescale O
#pragma unroll
        for (int dt = 0; dt < 4; dt++)
#pragma unroll
            for (int r = 0; r < 4; r++) o[dt][r] *= scl[r];

        if (kt < 63) issue(kt + 1);  // T14-lite: overlap HBM/L2 latency with PV

        // PV: O += P[16q][64kr] * V[64kr][64d]
#pragma unroll
        for (int kc = 0; kc < 2; kc++) {
            s16x8 pa = *(const s16x8*)(PsW + SWZ(lx, kc * 64 + g * 16));
#pragma unroll
            for (int dt = 0; dt < 4; dt++) {
                s16x8 vb = *(const s16x8*)((char*)Vs + SWZ(dt * 16 + lx, kc * 64 + g * 16));
                o[dt] = __builtin_amdgcn_mfma_f32_16x16x32_bf16(pa, vb, o[dt], 0, 0, 0);
            }
        }

        __syncthreads();
        if (kt < 63) {
            commit();
            __syncthreads();
        }
    }

    // epilogue: normalize + store
#pragma unroll
    for (int r = 0; r < 4; r++) {
        float inv = 1.0f / lreg[r];
        int qrow = qw + 4 * g + r;
#pragma unroll
        for (int dt = 0; dt < 4; dt++)
            att[(size_t)qrow * 256 + head * 64 + dt * 16 + lx] = o[dt][r] * inv;
    }
}

// ---------------------------------------------------------------------------
extern "C" void kernel_launch(void* const* d_in, const int* in_sizes, int n_in,
                              void* d_out, int out_size, void* d_ws, size_t ws_size,
                              hipStream_t stream) {
    const float* x0  = (const float*)d_in[0];
    const int*   eix = (const int*)d_in[1];
    const float* ew  = (const float*)d_in[2];
    const float* W1  = (const float*)d_in[3];
    const float* b1  = (const float*)d_in[4];
    const float* W2  = (const float*)d_in[5];
    const float* b2  = (const float*)d_in[6];
    const float* W3  = (const float*)d_in[7];
    const float* b3  = (const float*)d_in[8];
    const float* ipw = (const float*)d_in[9];
    const float* ipb = (const float*)d_in[10];
    const float* opw = (const float*)d_in[11];
    const float* opb = (const float*)d_in[12];
    float* out = (float*)d_out;

    char* ws = (char*)d_ws;
    size_t o = 0;
    auto alloc = [&](size_t bytes) -> void* {
        void* p = ws + o;
        o = (o + bytes + 255) & ~size_t(255);
        return p;
    };
    float* dinv  = (float*)alloc(N_NODES * 4);
    int*   cnt   = (int*)alloc(N_NODES * 4);
    int*   off   = (int*)alloc((N_NODES + 1) * 4);
    int*   fill  = (int*)alloc(N_NODES * 4);
    int*   srow  = (int*)alloc(N_EDGES * 4);
    float* snorm = (float*)alloc(N_EDGES * 4);
    float* H     = (float*)alloc((size_t)N_NODES * 256 * 4);
    float* QKV   = (float*)alloc((size_t)N_NODES * 768 * 4);
    float* XA    = (float*)alloc((size_t)N_NODES * 256 * 4);
    float* XB    = (float*)alloc((size_t)N_NODES * 256 * 4);
    unsigned short* Kb = (unsigned short*)alloc((size_t)4 * 4096 * 64 * 2);
    unsigned short* Vt = (unsigned short*)alloc((size_t)4 * 4096 * 64 * 2);

    const int* row = eix;
    const int* col = eix + N_EDGES;

    // graph preprocessing (shared by all 3 GCN layers)
    init_deg_cnt<<<16, 256, 0, stream>>>(dinv, cnt);
    deg_accum<<<512, 256, 0, stream>>>(col, ew, dinv, cnt);
    finalize_dinv<<<16, 256, 0, stream>>>(dinv);
    scan_offsets<<<1, 1024, 0, stream>>>(cnt, off, fill);
    scatter_edges<<<512, 256, 0, stream>>>(row, col, ew, dinv, fill, srow, snorm);

    dim3 thr(16, 16);
    // GCN layer 1
    gemm256<false, false, 0><<<dim3(4, 64), thr, 0, stream>>>(x0, W1, nullptr, H, 256);
    gcn_agg<256, 0><<<N_NODES, 256, 0, stream>>>(H, off, srow, snorm, dinv, b1, XA);
    // MHA 1 (+relu)
    gemm256<true, true, 0><<<dim3(12, 64), thr, 0, stream>>>(XA, ipw, ipb, QKV, 768);
    prep_kv<<<dim3(64, 4), 256, 0, stream>>>(QKV, Kb, Vt);
    attn_mfma<<<dim3(64, 4), 256, 0, stream>>>(QKV, Kb, Vt, H);
    gemm256<true, true, 1><<<dim3(4, 64), thr, 0, stream>>>(H, opw, opb, XB, 256);
    // GCN layer 2
    gemm256<false, false, 0><<<dim3(4, 64), thr, 0, stream>>>(XB, W2, nullptr, H, 256);
    gcn_agg<256, 0><<<N_NODES, 256, 0, stream>>>(H, off, srow, snorm, dinv, b2, XA);
    // MHA 2 (+relu)
    gemm256<true, true, 0><<<dim3(12, 64), thr, 0, stream>>>(XA, ipw, ipb, QKV, 768);
    prep_kv<<<dim3(64, 4), 256, 0, stream>>>(QKV, Kb, Vt);
    attn_mfma<<<dim3(64, 4), 256, 0, stream>>>(QKV, Kb, Vt, H);
    gemm256<true, true, 1><<<dim3(4, 64), thr, 0, stream>>>(H, opw, opb, XB, 256);
    // GCN layer 3 (+sigmoid) -> d_out
    gemm256<false, false, 0><<<dim3(2, 64), thr, 0, stream>>>(XB, W3, nullptr, H, 128);
    gcn_agg<128, 2><<<N_NODES, 128, 0, stream>>>(H, off, srow, snorm, dinv, b3, out);
}

// Round 4
// 414.685 us; speedup vs baseline: 6.4870x; 1.3332x over previous
//
#include <hip/hip_runtime.h>
#include <math.h>

#define N_NODES 4096
#define N_EDGES 262144
#define K_DIM 256

typedef __attribute__((ext_vector_type(4))) float f32x4;
typedef __attribute__((ext_vector_type(8))) short s16x8;

__device__ inline unsigned short f2bf(float f) {
    unsigned u = __builtin_bit_cast(unsigned, f);
    u += 0x7FFF + ((u >> 16) & 1);  // RNE
    return (unsigned short)(u >> 16);
}

// T2 XOR swizzle for 128-byte LDS rows
#define SWZ(row, colb) (((row) << 7) + ((colb) ^ (((row) & 7) << 4)))

// ---------------------------------------------------------------------------
// Graph preprocessing: degree, dinv, CSR by destination (col)
// ---------------------------------------------------------------------------
__global__ void init_deg_cnt(float* deg, int* cnt) {
    int i = blockIdx.x * blockDim.x + threadIdx.x;
    if (i < N_NODES) { deg[i] = 1.0f; cnt[i] = 0; }  // 1.0 = self-loop weight
}

__global__ void deg_accum(const int* __restrict__ col, const float* __restrict__ ew,
                          float* deg, int* cnt) {
    for (int e = blockIdx.x * blockDim.x + threadIdx.x; e < N_EDGES;
         e += gridDim.x * blockDim.x) {
        int c = col[e];
        atomicAdd(&deg[c], ew[e]);
        atomicAdd(&cnt[c], 1);
    }
}

__global__ void finalize_dinv(float* deg) {
    int i = blockIdx.x * blockDim.x + threadIdx.x;
    if (i < N_NODES) { float d = deg[i]; deg[i] = d > 0.f ? rsqrtf(d) : 0.f; }
}

__global__ __launch_bounds__(1024) void scan_offsets(const int* __restrict__ cnt,
                                                     int* off, int* fill) {
    __shared__ int s[1024];
    int tid = threadIdx.x;
    int c0 = cnt[tid * 4 + 0], c1 = cnt[tid * 4 + 1];
    int c2 = cnt[tid * 4 + 2], c3 = cnt[tid * 4 + 3];
    int lsum = c0 + c1 + c2 + c3;
    s[tid] = lsum;
    __syncthreads();
    for (int d = 1; d < 1024; d <<= 1) {
        int v = (tid >= d) ? s[tid - d] : 0;
        __syncthreads();
        s[tid] += v;
        __syncthreads();
    }
    int incl = s[tid];
    int base = incl - lsum;
    int o0 = base, o1 = base + c0, o2 = base + c0 + c1, o3 = base + c0 + c1 + c2;
    off[tid * 4 + 0] = o0;  fill[tid * 4 + 0] = o0;
    off[tid * 4 + 1] = o1;  fill[tid * 4 + 1] = o1;
    off[tid * 4 + 2] = o2;  fill[tid * 4 + 2] = o2;
    off[tid * 4 + 3] = o3;  fill[tid * 4 + 3] = o3;
    if (tid == 1023) off[4096] = incl;
}

__global__ void scatter_edges(const int* __restrict__ row, const int* __restrict__ col,
                              const float* __restrict__ ew, const float* __restrict__ dinv,
                              int* fill, int* srow, float* snorm) {
    for (int e = blockIdx.x * blockDim.x + threadIdx.x; e < N_EDGES;
         e += gridDim.x * blockDim.x) {
        int r = row[e], c = col[e];
        int p = atomicAdd(&fill[c], 1);
        srow[p] = r;
        snorm[p] = dinv[r] * ew[e] * dinv[c];
    }
}

// ---------------------------------------------------------------------------
// bf16 MFMA GEMM: C[N x P] = X[N x 256] @ B + (bias) (+relu)
//   BTRANS=false: B = W [256][P] row-major (GCN weights)
//   BTRANS=true : C = X @ W^T, W is [P][256] row-major (attn proj)
// 64x64 block tile, 4 waves (2x2), wave = 32x32 via 2x2 16x16x32 frags.
// fp32->bf16 conversion fused into LDS staging; fp32 accum; swizzled LDS.
// ---------------------------------------------------------------------------
template <bool BTRANS, bool BIAS, int ACT>
__global__ __launch_bounds__(256) void gemm_mfma(const float* __restrict__ X,
                                                 const float* __restrict__ W,
                                                 const float* __restrict__ bias,
                                                 float* __restrict__ C, int P) {
    __shared__ unsigned short As[64 * 64];  // [row][k] swizzled
    __shared__ unsigned short Bs[64 * 64];  // [n][k] swizzled
    int tid = threadIdx.x;
    int wid = tid >> 6, lane = tid & 63, g = lane >> 4, lx = lane & 15;
    int wr = wid >> 1, wc = wid & 1;
    int brow = blockIdx.y * 64, bcol = blockIdx.x * 64;

    f32x4 acc[2][2];
#pragma unroll
    for (int i = 0; i < 2; i++)
#pragma unroll
        for (int j = 0; j < 2; j++) acc[i][j] = f32x4{0.f, 0.f, 0.f, 0.f};

    for (int ks = 0; ks < 4; ks++) {
        int k0 = ks * 64;
        // ---- stage A (and B if BTRANS): rows of X / W, contiguous k ----
        {
            int r = tid >> 3, c8 = tid & 7;
#pragma unroll
            for (int h = 0; h < 2; h++) {
                int rr = r + h * 32;
                const float* src = X + (size_t)(brow + rr) * 256 + k0 + c8 * 8;
                s16x8 v;
#pragma unroll
                for (int i = 0; i < 8; i++) v[i] = (short)f2bf(src[i]);
                *(s16x8*)((char*)As + SWZ(rr, c8 * 16)) = v;
            }
            if (BTRANS) {
#pragma unroll
                for (int h = 0; h < 2; h++) {
                    int rr = r + h * 32;
                    const float* src = W + (size_t)(bcol + rr) * 256 + k0 + c8 * 8;
                    s16x8 v;
#pragma unroll
                    for (int i = 0; i < 8; i++) v[i] = (short)f2bf(src[i]);
                    *(s16x8*)((char*)Bs + SWZ(rr, c8 * 16)) = v;
                }
            } else {
                // Bs[n][k] = W[k][bcol+n]: lanes consecutive in n -> coalesced
                int n = tid & 63, cb = tid >> 6;
#pragma unroll
                for (int h = 0; h < 2; h++) {
                    int cc = cb + h * 4;
                    s16x8 v;
#pragma unroll
                    for (int i = 0; i < 8; i++)
                        v[i] = (short)f2bf(W[(size_t)(k0 + cc * 8 + i) * P + bcol + n]);
                    *(s16x8*)((char*)Bs + SWZ(n, cc * 16)) = v;
                }
            }
        }
        __syncthreads();
        __builtin_amdgcn_s_setprio(1);
#pragma unroll
        for (int kc = 0; kc < 2; kc++) {
            s16x8 a0 = *(const s16x8*)((char*)As + SWZ(wr * 32 + lx, kc * 64 + g * 16));
            s16x8 a1 = *(const s16x8*)((char*)As + SWZ(wr * 32 + 16 + lx, kc * 64 + g * 16));
            s16x8 b0 = *(const s16x8*)((char*)Bs + SWZ(wc * 32 + lx, kc * 64 + g * 16));
            s16x8 b1 = *(const s16x8*)((char*)Bs + SWZ(wc * 32 + 16 + lx, kc * 64 + g * 16));
            acc[0][0] = __builtin_amdgcn_mfma_f32_16x16x32_bf16(a0, b0, acc[0][0], 0, 0, 0);
            acc[0][1] = __builtin_amdgcn_mfma_f32_16x16x32_bf16(a0, b1, acc[0][1], 0, 0, 0);
            acc[1][0] = __builtin_amdgcn_mfma_f32_16x16x32_bf16(a1, b0, acc[1][0], 0, 0, 0);
            acc[1][1] = __builtin_amdgcn_mfma_f32_16x16x32_bf16(a1, b1, acc[1][1], 0, 0, 0);
        }
        __builtin_amdgcn_s_setprio(0);
        __syncthreads();
    }
    // epilogue: C/D layout col=lane&15, row=(lane>>4)*4+reg
#pragma unroll
    for (int mi = 0; mi < 2; mi++)
#pragma unroll
        for (int nj = 0; nj < 2; nj++)
#pragma unroll
            for (int rr = 0; rr < 4; rr++) {
                int r = brow + wr * 32 + mi * 16 + g * 4 + rr;
                int c = bcol + wc * 32 + nj * 16 + lx;
                float v = acc[mi][nj][rr];
                if (BIAS) v += bias[c];
                if (ACT == 1) v = fmaxf(v, 0.f);
                C[(size_t)r * P + c] = v;
            }
}

// ---------------------------------------------------------------------------
// GCN aggregation: out[i] = sum_in-edges norm*H[row] + dinv[i]^2*H[i] + bias
// ---------------------------------------------------------------------------
template <int P, int ACT>
__global__ void gcn_agg(const float* __restrict__ H, const int* __restrict__ off,
                        const int* __restrict__ srow, const float* __restrict__ snorm,
                        const float* __restrict__ dinv, const float* __restrict__ bias,
                        float* __restrict__ out) {
    __shared__ int sr[256];
    __shared__ float sw[256];
    int i = blockIdx.x, tid = threadIdx.x;
    float di = dinv[i];
    float acc = di * di * H[i * P + tid];
    int beg = off[i], end = off[i + 1];
    for (int base = beg; base < end; base += P) {
        int n = min(P, end - base);
        __syncthreads();
        if (tid < n) { sr[tid] = srow[base + tid]; sw[tid] = snorm[base + tid]; }
        __syncthreads();
#pragma unroll 4
        for (int j = 0; j < n; j++) acc += sw[j] * H[sr[j] * P + tid];
    }
    float v = acc + bias[tid];
    if (ACT == 2) v = 1.f / (1.f + __expf(-v));
    out[i * P + tid] = v;
}

// ---------------------------------------------------------------------------
// MHA prep: K -> bf16 [head][n][64]; V -> bf16 transposed [head][d][n]
// ---------------------------------------------------------------------------
__global__ __launch_bounds__(256) void prep_kv(const float* __restrict__ qkv,
                                               unsigned short* __restrict__ Kb,
                                               unsigned short* __restrict__ Vt) {
    __shared__ float vt[64][65];
    int head = blockIdx.y, n0 = blockIdx.x * 64, tid = threadIdx.x;
#pragma unroll
    for (int it = 0; it < 16; ++it) {
        int idx = tid + it * 256;
        int r = idx >> 6, c = idx & 63;
        const float* src = qkv + (size_t)(n0 + r) * 768 + head * 64;
        Kb[(size_t)(head * 4096 + n0 + r) * 64 + c] = f2bf(src[256 + c]);
        vt[c][r] = src[512 + c];
    }
    __syncthreads();
#pragma unroll
    for (int it = 0; it < 16; ++it) {
        int idx = tid + it * 256;
        int d = idx >> 6, c = idx & 63;
        Vt[(size_t)(head * 64 + d) * 4096 + n0 + c] = f2bf(vt[d][c]);
    }
}

// ---------------------------------------------------------------------------
// MFMA flash attention, flash-decoding split over 4 KV chunks.
// grid (64 q-tiles, 4 heads, 4 chunks), 256 threads = 4 waves x 16 q-rows.
// Writes UN-normalized partial O + (m, l) in exp2 domain to workspace.
// ---------------------------------------------------------------------------
__global__ __launch_bounds__(256) void attn_mfma(const float* __restrict__ qkv,
                                                 const unsigned short* __restrict__ Kb,
                                                 const unsigned short* __restrict__ Vt,
                                                 float* __restrict__ Po,
                                                 float* __restrict__ Pm,
                                                 float* __restrict__ Pl) {
    __shared__ unsigned short Ks[64 * 64];   // [kr][d] swizzled
    __shared__ unsigned short Vs[64 * 64];   // [d][kr] swizzled (V^T)
    __shared__ unsigned short Ps[4][16 * 64];  // per-wave P [q][kr] swizzled

    int tid = threadIdx.x;
    int wid = tid >> 6, lane = tid & 63, g = lane >> 4, lx = lane & 15;
    int head = blockIdx.y, chunk = blockIdx.z;
    int qw = blockIdx.x * 64 + wid * 16;   // wave's 16 q-rows

    // Q a-frags, pre-scaled by log2(e)/sqrt(64) -> exp2-domain scores
    s16x8 qa[2];
    {
        const float* qp = qkv + (size_t)(qw + lx) * 768 + head * 64 + g * 8;
#pragma unroll
        for (int kc = 0; kc < 2; kc++) {
            const float* p = qp + kc * 32;
            s16x8 v;
#pragma unroll
            for (int i = 0; i < 8; i++) v[i] = (short)f2bf(p[i] * 0.180337f);  // 0.125*log2(e)
            qa[kc] = v;
        }
    }

    const unsigned short* KbH = Kb + (size_t)head * 4096 * 64;
    const unsigned short* VtH = Vt + (size_t)head * 64 * 4096;

    int kr0 = tid >> 3, dc0 = tid & 7;
    int kr1 = kr0 + 32;
    s16x8 stK[2], stV[2];
    auto issue = [&](int kt) {
        stK[0] = *(const s16x8*)(KbH + (size_t)(kt * 64 + kr0) * 64 + dc0 * 8);
        stK[1] = *(const s16x8*)(KbH + (size_t)(kt * 64 + kr1) * 64 + dc0 * 8);
        stV[0] = *(const s16x8*)(VtH + (size_t)kr0 * 4096 + kt * 64 + dc0 * 8);
        stV[1] = *(const s16x8*)(VtH + (size_t)kr1 * 4096 + kt * 64 + dc0 * 8);
    };
    auto commit = [&]() {
        *(s16x8*)((char*)Ks + SWZ(kr0, dc0 * 16)) = stK[0];
        *(s16x8*)((char*)Ks + SWZ(kr1, dc0 * 16)) = stK[1];
        *(s16x8*)((char*)Vs + SWZ(kr0, dc0 * 16)) = stV[0];
        *(s16x8*)((char*)Vs + SWZ(kr1, dc0 * 16)) = stV[1];
    };

    float mreg[4] = {-1e30f, -1e30f, -1e30f, -1e30f};
    float lreg[4] = {0.f, 0.f, 0.f, 0.f};
    f32x4 o[4];
#pragma unroll
    for (int dt = 0; dt < 4; dt++) o[dt] = f32x4{0.f, 0.f, 0.f, 0.f};

    char* PsW = (char*)Ps + wid * (16 * 64 * 2);

    int kt_beg = chunk * 16, kt_end = kt_beg + 16;
    issue(kt_beg);
    commit();
    __syncthreads();

    for (int kt = kt_beg; kt < kt_end; kt++) {
        // QK^T: S[16q][64kr] (exp2 domain)
        f32x4 s4[4];
        __builtin_amdgcn_s_setprio(1);
#pragma unroll
        for (int nt = 0; nt < 4; nt++) {
            f32x4 acc = f32x4{0.f, 0.f, 0.f, 0.f};
#pragma unroll
            for (int kc = 0; kc < 2; kc++) {
                s16x8 kb = *(const s16x8*)((char*)Ks + SWZ(nt * 16 + lx, kc * 64 + g * 16));
                acc = __builtin_amdgcn_mfma_f32_16x16x32_bf16(qa[kc], kb, acc, 0, 0, 0);
            }
            s4[nt] = acc;
        }
        __builtin_amdgcn_s_setprio(0);

        // online softmax, defer-rescale (T13, THR=8 in exp2 domain)
        float pmr[4];
#pragma unroll
        for (int r = 0; r < 4; r++) {
            float pm = fmaxf(fmaxf(s4[0][r], s4[1][r]), fmaxf(s4[2][r], s4[3][r]));
            pm = fmaxf(pm, __shfl_xor(pm, 1, 16));
            pm = fmaxf(pm, __shfl_xor(pm, 2, 16));
            pm = fmaxf(pm, __shfl_xor(pm, 4, 16));
            pm = fmaxf(pm, __shfl_xor(pm, 8, 16));
            pmr[r] = pm;
        }
        bool grow = false;
#pragma unroll
        for (int r = 0; r < 4; r++) grow |= (pmr[r] > mreg[r] + 8.0f);
        if (__any(grow)) {
#pragma unroll
            for (int r = 0; r < 4; r++) {
                float mn = fmaxf(mreg[r], pmr[r]);
                float sc = exp2f(mreg[r] - mn);
                mreg[r] = mn;
                lreg[r] *= sc;
#pragma unroll
                for (int dt = 0; dt < 4; dt++) o[dt][r] *= sc;
            }
        }
#pragma unroll
        for (int r = 0; r < 4; r++) {
            float ps = 0.f;
#pragma unroll
            for (int nt = 0; nt < 4; nt++) {
                float p = exp2f(s4[nt][r] - mreg[r]);
                s4[nt][r] = p;
                ps += p;
            }
            ps += __shfl_xor(ps, 1, 16);
            ps += __shfl_xor(ps, 2, 16);
            ps += __shfl_xor(ps, 4, 16);
            ps += __shfl_xor(ps, 8, 16);
            lreg[r] += ps;
        }
        // write P (bf16) to wave-private LDS
#pragma unroll
        for (int nt = 0; nt < 4; nt++)
#pragma unroll
            for (int r = 0; r < 4; r++)
                *(unsigned short*)(PsW + SWZ(4 * g + r, (nt * 16 + lx) * 2)) =
                    f2bf(s4[nt][r]);

        if (kt + 1 < kt_end) issue(kt + 1);  // T14-lite overlap

        // PV: O += P[16q][64kr] * V[64kr][64d]
        __builtin_amdgcn_s_setprio(1);
#pragma unroll
        for (int kc = 0; kc < 2; kc++) {
            s16x8 pa = *(const s16x8*)(PsW + SWZ(lx, kc * 64 + g * 16));
#pragma unroll
            for (int dt = 0; dt < 4; dt++) {
                s16x8 vb = *(const s16x8*)((char*)Vs + SWZ(dt * 16 + lx, kc * 64 + g * 16));
                o[dt] = __builtin_amdgcn_mfma_f32_16x16x32_bf16(pa, vb, o[dt], 0, 0, 0);
            }
        }
        __builtin_amdgcn_s_setprio(0);

        __syncthreads();
        if (kt + 1 < kt_end) {
            commit();
            __syncthreads();
        }
    }

    // epilogue: write un-normalized partial + (m, l)
#pragma unroll
    for (int r = 0; r < 4; r++) {
        int qrow = qw + 4 * g + r;
        size_t base = (size_t)(chunk * 4 + head) * 4096 + qrow;
        if (lx == 0) { Pm[base] = mreg[r]; Pl[base] = lreg[r]; }
#pragma unroll
        for (int dt = 0; dt < 4; dt++)
            Po[base * 64 + dt * 16 + lx] = o[dt][r];
    }
}

// ---------------------------------------------------------------------------
// Combine 4 chunk-partials -> att [N][256]
// grid (64 q-tiles, 4 heads), 256 threads
// ---------------------------------------------------------------------------
__global__ __launch_bounds__(256) void attn_combine(const float* __restrict__ Po,
                                                    const float* __restrict__ Pm,
                                                    const float* __restrict__ Pl,
                                                    float* __restrict__ att) {
    int head = blockIdx.y, q0 = blockIdx.x * 64;
    int d = threadIdx.x & 63, qo = threadIdx.x >> 6;
#pragma unroll 4
    for (int rr = 0; rr < 16; rr++) {
        int q = q0 + qo + rr * 4;
        float mc[4], lc[4];
#pragma unroll
        for (int c = 0; c < 4; c++) {
            size_t base = (size_t)(c * 4 + head) * 4096 + q;
            mc[c] = Pm[base];
            lc[c] = Pl[base];
        }
        float M = fmaxf(fmaxf(mc[0], mc[1]), fmaxf(mc[2], mc[3]));
        float L = 0.f, ov = 0.f;
#pragma unroll
        for (int c = 0; c < 4; c++) {
            float w = exp2f(mc[c] - M);
            L += w * lc[c];
            ov += w * Po[((size_t)(c * 4 + head) * 4096 + q) * 64 + d];
        }
        att[(size_t)q * 256 + head * 64 + d] = ov / L;
    }
}

// ---------------------------------------------------------------------------
extern "C" void kernel_launch(void* const* d_in, const int* in_sizes, int n_in,
                              void* d_out, int out_size, void* d_ws, size_t ws_size,
                              hipStream_t stream) {
    const float* x0  = (const float*)d_in[0];
    const int*   eix = (const int*)d_in[1];
    const float* ew  = (const float*)d_in[2];
    const float* W1  = (const float*)d_in[3];
    const float* b1  = (const float*)d_in[4];
    const float* W2  = (const float*)d_in[5];
    const float* b2  = (const float*)d_in[6];
    const float* W3  = (const float*)d_in[7];
    const float* b3  = (const float*)d_in[8];
    const float* ipw = (const float*)d_in[9];
    const float* ipb = (const float*)d_in[10];
    const float* opw = (const float*)d_in[11];
    const float* opb = (const float*)d_in[12];
    float* out = (float*)d_out;

    char* ws = (char*)d_ws;
    size_t o = 0;
    auto alloc = [&](size_t bytes) -> void* {
        void* p = ws + o;
        o = (o + bytes + 255) & ~size_t(255);
        return p;
    };
    float* dinv  = (float*)alloc(N_NODES * 4);
    int*   cnt   = (int*)alloc(N_NODES * 4);
    int*   off   = (int*)alloc((N_NODES + 1) * 4);
    int*   fill  = (int*)alloc(N_NODES * 4);
    int*   srow  = (int*)alloc(N_EDGES * 4);
    float* snorm = (float*)alloc(N_EDGES * 4);
    float* H     = (float*)alloc((size_t)N_NODES * 256 * 4);
    float* QKV   = (float*)alloc((size_t)N_NODES * 768 * 4);
    float* XA    = (float*)alloc((size_t)N_NODES * 256 * 4);
    float* XB    = (float*)alloc((size_t)N_NODES * 256 * 4);
    unsigned short* Kb = (unsigned short*)alloc((size_t)4 * 4096 * 64 * 2);
    unsigned short* Vt = (unsigned short*)alloc((size_t)4 * 4096 * 64 * 2);
    float* Po = (float*)alloc((size_t)16 * 4096 * 64 * 4);
    float* Pm = (float*)alloc((size_t)16 * 4096 * 4);
    float* Pl = (float*)alloc((size_t)16 * 4096 * 4);

    const int* row = eix;
    const int* col = eix + N_EDGES;

    // graph preprocessing (shared by all 3 GCN layers)
    init_deg_cnt<<<16, 256, 0, stream>>>(dinv, cnt);
    deg_accum<<<512, 256, 0, stream>>>(col, ew, dinv, cnt);
    finalize_dinv<<<16, 256, 0, stream>>>(dinv);
    scan_offsets<<<1, 1024, 0, stream>>>(cnt, off, fill);
    scatter_edges<<<512, 256, 0, stream>>>(row, col, ew, dinv, fill, srow, snorm);

    // GCN layer 1
    gemm_mfma<false, false, 0><<<dim3(4, 64), 256, 0, stream>>>(x0, W1, nullptr, H, 256);
    gcn_agg<256, 0><<<N_NODES, 256, 0, stream>>>(H, off, srow, snorm, dinv, b1, XA);
    // MHA 1 (+relu)
    gemm_mfma<true, true, 0><<<dim3(12, 64), 256, 0, stream>>>(XA, ipw, ipb, QKV, 768);
    prep_kv<<<dim3(64, 4), 256, 0, stream>>>(QKV, Kb, Vt);
    attn_mfma<<<dim3(64, 4, 4), 256, 0, stream>>>(QKV, Kb, Vt, Po, Pm, Pl);
    attn_combine<<<dim3(64, 4), 256, 0, stream>>>(Po, Pm, Pl, H);
    gemm_mfma<true, true, 1><<<dim3(4, 64), 256, 0, stream>>>(H, opw, opb, XB, 256);
    // GCN layer 2
    gemm_mfma<false, false, 0><<<dim3(4, 64), 256, 0, stream>>>(XB, W2, nullptr, H, 256);
    gcn_agg<256, 0><<<N_NODES, 256, 0, stream>>>(H, off, srow, snorm, dinv, b2, XA);
    // MHA 2 (+relu)
    gemm_mfma<true, true, 0><<<dim3(12, 64), 256, 0, stream>>>(XA, ipw, ipb, QKV, 768);
    prep_kv<<<dim3(64, 4), 256, 0, stream>>>(QKV, Kb, Vt);
    attn_mfma<<<dim3(64, 4, 4), 256, 0, stream>>>(QKV, Kb, Vt, Po, Pm, Pl);
    attn_combine<<<dim3(64, 4), 256, 0, stream>>>(Po, Pm, Pl, H);
    gemm_mfma<true, true, 1><<<dim3(4, 64), 256, 0, stream>>>(H, opw, opb, XB, 256);
    // GCN layer 3 (+sigmoid) -> d_out
    gemm_mfma<false, false, 0><<<dim3(2, 64), 256, 0, stream>>>(XB, W3, nullptr, H, 128);
    gcn_agg<128, 2><<<N_NODES, 128, 0, stream>>>(H, off, srow, snorm, dinv, b3, out);
}

// Round 5
// 354.929 us; speedup vs baseline: 7.5791x; 1.1684x over previous
//
#include <hip/hip_runtime.h>
#include <math.h>

#define N_NODES 4096
#define N_EDGES 262144

typedef __attribute__((ext_vector_type(4))) float f32x4;
typedef __attribute__((ext_vector_type(8))) short s16x8;
typedef __attribute__((ext_vector_type(4))) unsigned short u16x4;

__device__ inline unsigned short f2bf(float f) {
    unsigned u = __builtin_bit_cast(unsigned, f);
    u += 0x7FFF + ((u >> 16) & 1);  // RNE
    return (unsigned short)(u >> 16);
}
__device__ inline float bf2f(unsigned short u) {
    unsigned x = ((unsigned)u) << 16;
    return __builtin_bit_cast(float, x);
}

// T2 XOR swizzle for 128-byte LDS rows
#define SWZ(row, colb) (((row) << 7) + ((colb) ^ (((row) & 7) << 4)))

// ---------------------------------------------------------------------------
// Graph preprocessing: degree, dinv, CSR by destination (col)
// ---------------------------------------------------------------------------
__global__ void init_deg_cnt(float* deg, int* cnt) {
    int i = blockIdx.x * blockDim.x + threadIdx.x;
    if (i < N_NODES) { deg[i] = 1.0f; cnt[i] = 0; }  // 1.0 = self-loop weight
}

__global__ void deg_accum(const int* __restrict__ col, const float* __restrict__ ew,
                          float* deg, int* cnt) {
    for (int e = blockIdx.x * blockDim.x + threadIdx.x; e < N_EDGES;
         e += gridDim.x * blockDim.x) {
        int c = col[e];
        atomicAdd(&deg[c], ew[e]);
        atomicAdd(&cnt[c], 1);
    }
}

__global__ void finalize_dinv(float* deg) {
    int i = blockIdx.x * blockDim.x + threadIdx.x;
    if (i < N_NODES) { float d = deg[i]; deg[i] = d > 0.f ? rsqrtf(d) : 0.f; }
}

__global__ __launch_bounds__(1024) void scan_offsets(const int* __restrict__ cnt,
                                                     int* off, int* fill) {
    __shared__ int s[1024];
    int tid = threadIdx.x;
    int c0 = cnt[tid * 4 + 0], c1 = cnt[tid * 4 + 1];
    int c2 = cnt[tid * 4 + 2], c3 = cnt[tid * 4 + 3];
    int lsum = c0 + c1 + c2 + c3;
    s[tid] = lsum;
    __syncthreads();
    for (int d = 1; d < 1024; d <<= 1) {
        int v = (tid >= d) ? s[tid - d] : 0;
        __syncthreads();
        s[tid] += v;
        __syncthreads();
    }
    int incl = s[tid];
    int base = incl - lsum;
    int o0 = base, o1 = base + c0, o2 = base + c0 + c1, o3 = base + c0 + c1 + c2;
    off[tid * 4 + 0] = o0;  fill[tid * 4 + 0] = o0;
    off[tid * 4 + 1] = o1;  fill[tid * 4 + 1] = o1;
    off[tid * 4 + 2] = o2;  fill[tid * 4 + 2] = o2;
    off[tid * 4 + 3] = o3;  fill[tid * 4 + 3] = o3;
    if (tid == 1023) off[4096] = incl;
}

__global__ void scatter_edges(const int* __restrict__ row, const int* __restrict__ col,
                              const float* __restrict__ ew, const float* __restrict__ dinv,
                              int* fill, int* srow, float* snorm) {
    for (int e = blockIdx.x * blockDim.x + threadIdx.x; e < N_EDGES;
         e += gridDim.x * blockDim.x) {
        int r = row[e], c = col[e];
        int p = atomicAdd(&fill[c], 1);
        srow[p] = r;
        snorm[p] = dinv[r] * ew[e] * dinv[c];
    }
}

// ---------------------------------------------------------------------------
// One-time per-call weight/input conversions
// ---------------------------------------------------------------------------
__global__ void conv_bf16(const float* __restrict__ s, unsigned short* __restrict__ d, int n) {
    int i = (blockIdx.x * 256 + threadIdx.x) * 4;
    if (i < n) {
        f32x4 v = *(const f32x4*)(s + i);
        u16x4 o;
#pragma unroll
        for (int j = 0; j < 4; j++) o[j] = f2bf(v[j]);
        *(u16x4*)(d + i) = o;
    }
}

// in_proj_w [768][256]: convert, scaling K-rows (256..511) by 0.125*log2(e)
__global__ void conv_ipw(const float* __restrict__ s, unsigned short* __restrict__ d) {
    int i = (blockIdx.x * 256 + threadIdx.x) * 4;
    int r = i >> 8;
    float sc = (r >= 256 && r < 512) ? 0.1803369f : 1.0f;
    f32x4 v = *(const f32x4*)(s + i);
    u16x4 o;
#pragma unroll
    for (int j = 0; j < 4; j++) o[j] = f2bf(v[j] * sc);
    *(u16x4*)(d + i) = o;
}

__global__ void scale_ipb(const float* __restrict__ s, float* __restrict__ d) {
    int i = threadIdx.x;  // 768
    float sc = (i >= 256 && i < 512) ? 0.1803369f : 1.0f;
    d[i] = s[i] * sc;
}

// W [256][P] fp32 -> Wt [P][256] bf16
__global__ __launch_bounds__(256) void transpose_w(const float* __restrict__ s,
                                                   unsigned short* __restrict__ d, int P) {
    __shared__ float t[32][33];
    int tx = threadIdx.x, ty = threadIdx.y;  // 32 x 8
    int r0 = blockIdx.y * 32, c0 = blockIdx.x * 32;
#pragma unroll
    for (int q = 0; q < 4; q++)
        t[ty + q * 8][tx] = s[(size_t)(r0 + ty + q * 8) * P + c0 + tx];
    __syncthreads();
#pragma unroll
    for (int q = 0; q < 4; q++)
        d[(size_t)(c0 + ty + q * 8) * 256 + r0 + tx] = f2bf(t[tx][ty + q * 8]);
}

// ---------------------------------------------------------------------------
// Single-wave bf16 GEMM: C[16 x 64 tile] = A[N][256] @ B^T, B = [P][256] bf16
// No LDS, no barriers: fragments loaded straight from global (L2-resident).
// grid (P/64, N/16), 64 threads.
// ---------------------------------------------------------------------------
template <bool BIAS, int ACT>
__global__ __launch_bounds__(64) void gemm_bf16(const unsigned short* __restrict__ A,
                                                const unsigned short* __restrict__ B,
                                                const float* __restrict__ bias,
                                                unsigned short* __restrict__ C, int P) {
    int lane = threadIdx.x & 63;
    int lx = lane & 15, g = lane >> 4;
    int brow = blockIdx.y * 16, bcol = blockIdx.x * 64;
    const unsigned short* Ap = A + (size_t)(brow + lx) * 256 + g * 8;
    const unsigned short* Bp = B + (size_t)(bcol + lx) * 256 + g * 8;
    f32x4 acc[4];
#pragma unroll
    for (int nt = 0; nt < 4; nt++) acc[nt] = f32x4{0.f, 0.f, 0.f, 0.f};
#pragma unroll
    for (int kc = 0; kc < 8; kc++) {
        s16x8 a = *(const s16x8*)(Ap + kc * 32);
#pragma unroll
        for (int nt = 0; nt < 4; nt++) {
            s16x8 b = *(const s16x8*)(Bp + (size_t)nt * 16 * 256 + kc * 32);
            acc[nt] = __builtin_amdgcn_mfma_f32_16x16x32_bf16(a, b, acc[nt], 0, 0, 0);
        }
    }
#pragma unroll
    for (int nt = 0; nt < 4; nt++)
#pragma unroll
        for (int r = 0; r < 4; r++) {
            int row = brow + g * 4 + r, col = bcol + nt * 16 + lx;
            float v = acc[nt][r];
            if (BIAS) v += bias[col];
            if (ACT == 1) v = fmaxf(v, 0.f);
            C[(size_t)row * P + col] = f2bf(v);
        }
}

// ---------------------------------------------------------------------------
// GCN aggregation: out[i] = sum norm*H[row] + dinv[i]^2*H[i] + bias (bf16 in)
// ---------------------------------------------------------------------------
template <int P, bool SIG>
__global__ void gcn_agg(const unsigned short* __restrict__ H, const int* __restrict__ off,
                        const int* __restrict__ srow, const float* __restrict__ snorm,
                        const float* __restrict__ dinv, const float* __restrict__ bias,
                        unsigned short* __restrict__ outb, float* __restrict__ outf) {
    __shared__ int sr[P];
    __shared__ float sw[P];
    int i = blockIdx.x, tid = threadIdx.x;
    float di = dinv[i];
    float acc = di * di * bf2f(H[(size_t)i * P + tid]);
    int beg = off[i], end = off[i + 1];
    for (int base = beg; base < end; base += P) {
        int n = min(P, end - base);
        __syncthreads();
        if (tid < n) { sr[tid] = srow[base + tid]; sw[tid] = snorm[base + tid]; }
        __syncthreads();
#pragma unroll 4
        for (int j = 0; j < n; j++) acc += sw[j] * bf2f(H[(size_t)sr[j] * P + tid]);
    }
    float v = acc + bias[tid];
    if (SIG) {
        v = 1.f / (1.f + exp2f(-v * 1.442695f));
        outf[(size_t)i * P + tid] = v;
    } else {
        outb[(size_t)i * P + tid] = f2bf(v);
    }
}

// ---------------------------------------------------------------------------
// V transpose: qkv bf16 [N][768] -> Vt bf16 [head][d][n]
// ---------------------------------------------------------------------------
__global__ __launch_bounds__(256) void prep_v(const unsigned short* __restrict__ qkv,
                                              unsigned short* __restrict__ Vt) {
    __shared__ unsigned short vt[64][66];
    int head = blockIdx.y, n0 = blockIdx.x * 64, tid = threadIdx.x;
#pragma unroll
    for (int it = 0; it < 16; ++it) {
        int idx = tid + it * 256;
        int r = idx >> 6, c = idx & 63;
        vt[c][r] = qkv[(size_t)(n0 + r) * 768 + 512 + head * 64 + c];
    }
    __syncthreads();
#pragma unroll
    for (int it = 0; it < 16; ++it) {
        int idx = tid + it * 256;
        int d = idx >> 6, c = idx & 63;
        Vt[(size_t)(head * 64 + d) * 4096 + n0 + c] = vt[d][c];
    }
}

// ---------------------------------------------------------------------------
// MFMA flash attention, fixed-base softmax (scores provably tiny; clamp guards
// overflow), per-lane deferred l-sum, double-buffered K/V (1 barrier / tile).
// grid (64 q-tiles, 4 heads, 4 chunks), 256 threads = 4 waves x 16 q-rows.
// K is staged directly from qkv (scale pre-folded into in_proj K rows).
// ---------------------------------------------------------------------------
__global__ __launch_bounds__(256) void attn_mfma(const unsigned short* __restrict__ qkv,
                                                 const unsigned short* __restrict__ Vt,
                                                 unsigned short* __restrict__ Po,
                                                 float* __restrict__ Pl) {
    __shared__ unsigned short Ks[2][64 * 64];   // [kr][d] swizzled
    __shared__ unsigned short Vs[2][64 * 64];   // [d][kr] swizzled (V^T)
    __shared__ unsigned short Ps[4][16 * 64];   // per-wave P [q][kr] swizzled

    int tid = threadIdx.x;
    int wid = tid >> 6, lane = tid & 63, g = lane >> 4, lx = lane & 15;
    int head = blockIdx.y, chunk = blockIdx.z;
    int qw = blockIdx.x * 64 + wid * 16;   // wave's 16 q-rows

    // Q a-frags straight from bf16 qkv (K carries the softmax scale)
    s16x8 qa[2];
#pragma unroll
    for (int kc = 0; kc < 2; kc++)
        qa[kc] = *(const s16x8*)(qkv + (size_t)(qw + lx) * 768 + head * 64 + kc * 32 + g * 8);

    const unsigned short* Kg = qkv + 256 + head * 64;          // K cols in qkv rows
    const unsigned short* VtH = Vt + (size_t)head * 64 * 4096;

    int kr0 = tid >> 3, dc0 = tid & 7;   // kr0 0..31, dc0 0..7
    int kr1 = kr0 + 32;
    s16x8 stK[2], stV[2];
    auto issue = [&](int kt) {
        stK[0] = *(const s16x8*)(Kg + (size_t)(kt * 64 + kr0) * 768 + dc0 * 8);
        stK[1] = *(const s16x8*)(Kg + (size_t)(kt * 64 + kr1) * 768 + dc0 * 8);
        stV[0] = *(const s16x8*)(VtH + (size_t)kr0 * 4096 + kt * 64 + dc0 * 8);
        stV[1] = *(const s16x8*)(VtH + (size_t)kr1 * 4096 + kt * 64 + dc0 * 8);
    };
    auto commit = [&](int b) {
        *(s16x8*)((char*)Ks[b] + SWZ(kr0, dc0 * 16)) = stK[0];
        *(s16x8*)((char*)Ks[b] + SWZ(kr1, dc0 * 16)) = stK[1];
        *(s16x8*)((char*)Vs[b] + SWZ(kr0, dc0 * 16)) = stV[0];
        *(s16x8*)((char*)Vs[b] + SWZ(kr1, dc0 * 16)) = stV[1];
    };

    float lreg[4] = {0.f, 0.f, 0.f, 0.f};
    f32x4 o[4];
#pragma unroll
    for (int dt = 0; dt < 4; dt++) o[dt] = f32x4{0.f, 0.f, 0.f, 0.f};

    char* PsW = (char*)Ps[wid];

    int kt_beg = chunk * 16, kt_end = kt_beg + 16;
    issue(kt_beg);
    commit(0);
    __syncthreads();

    for (int kt = kt_beg; kt < kt_end; kt++) {
        int cur = (kt - kt_beg) & 1;
        if (kt + 1 < kt_end) issue(kt + 1);  // loads in flight across compute

        // QK^T: S[16q][64kr] (exp2 domain, scale folded into K)
        f32x4 s4[4];
        __builtin_amdgcn_s_setprio(1);
#pragma unroll
        for (int nt = 0; nt < 4; nt++) {
            f32x4 acc = f32x4{0.f, 0.f, 0.f, 0.f};
#pragma unroll
            for (int kc = 0; kc < 2; kc++) {
                s16x8 kb = *(const s16x8*)((char*)Ks[cur] + SWZ(nt * 16 + lx, kc * 64 + g * 16));
                acc = __builtin_amdgcn_mfma_f32_16x16x32_bf16(qa[kc], kb, acc, 0, 0, 0);
            }
            s4[nt] = acc;
        }
        __builtin_amdgcn_s_setprio(0);

        // fixed-base softmax: P = exp2(min(s,60)); l accumulated per-lane
#pragma unroll
        for (int nt = 0; nt < 4; nt++)
#pragma unroll
            for (int r = 0; r < 4; r++) {
                float p = exp2f(fminf(s4[nt][r], 60.f));
                lreg[r] += p;
                *(unsigned short*)(PsW + SWZ(4 * g + r, (nt * 16 + lx) * 2)) = f2bf(p);
            }

        // PV: O += P[16q][64kr] * V[64kr][64d]
        __builtin_amdgcn_s_setprio(1);
#pragma unroll
        for (int kc = 0; kc < 2; kc++) {
            s16x8 pa = *(const s16x8*)(PsW + SWZ(lx, kc * 64 + g * 16));
#pragma unroll
            for (int dt = 0; dt < 4; dt++) {
                s16x8 vb = *(const s16x8*)((char*)Vs[cur] + SWZ(dt * 16 + lx, kc * 64 + g * 16));
                o[dt] = __builtin_amdgcn_mfma_f32_16x16x32_bf16(pa, vb, o[dt], 0, 0, 0);
            }
        }
        __builtin_amdgcn_s_setprio(0);

        if (kt + 1 < kt_end) commit(1 - cur);
        __syncthreads();   // single barrier per tile (double-buffered)
    }

    // epilogue: reduce l over the 16 lanes of each g-group; write partials
#pragma unroll
    for (int r = 0; r < 4; r++) {
        float ls = lreg[r];
        ls += __shfl_xor(ls, 1, 16);
        ls += __shfl_xor(ls, 2, 16);
        ls += __shfl_xor(ls, 4, 16);
        ls += __shfl_xor(ls, 8, 16);
        int qrow = qw + 4 * g + r;
        size_t base = (size_t)(chunk * 4 + head) * 4096 + qrow;
        if (lx == 0) Pl[base] = ls;
#pragma unroll
        for (int dt = 0; dt < 4; dt++)
            Po[base * 64 + dt * 16 + lx] = f2bf(o[dt][r]);
    }
}

// ---------------------------------------------------------------------------
// Combine 4 chunk-partials (plain sums) -> att bf16 [N][256]
// ---------------------------------------------------------------------------
__global__ __launch_bounds__(256) void attn_combine(const unsigned short* __restrict__ Po,
                                                    const float* __restrict__ Pl,
                                                    unsigned short* __restrict__ att) {
    int q = blockIdx.x;
    int head = threadIdx.x >> 6, d = threadIdx.x & 63;
    float L = 0.f, ov = 0.f;
#pragma unroll
    for (int c = 0; c < 4; c++) {
        size_t base = (size_t)(c * 4 + head) * 4096 + q;
        L += Pl[base];
        ov += bf2f(Po[base * 64 + d]);
    }
    att[(size_t)q * 256 + head * 64 + d] = f2bf(ov / L);
}

// ---------------------------------------------------------------------------
extern "C" void kernel_launch(void* const* d_in, const int* in_sizes, int n_in,
                              void* d_out, int out_size, void* d_ws, size_t ws_size,
                              hipStream_t stream) {
    const float* x0  = (const float*)d_in[0];
    const int*   eix = (const int*)d_in[1];
    const float* ew  = (const float*)d_in[2];
    const float* W1  = (const float*)d_in[3];
    const float* b1  = (const float*)d_in[4];
    const float* W2  = (const float*)d_in[5];
    const float* b2  = (const float*)d_in[6];
    const float* W3  = (const float*)d_in[7];
    const float* b3  = (const float*)d_in[8];
    const float* ipw = (const float*)d_in[9];
    const float* ipb = (const float*)d_in[10];
    const float* opw = (const float*)d_in[11];
    const float* opb = (const float*)d_in[12];
    float* out = (float*)d_out;

    char* ws = (char*)d_ws;
    size_t o = 0;
    auto alloc = [&](size_t bytes) -> void* {
        void* p = ws + o;
        o = (o + bytes + 255) & ~size_t(255);
        return p;
    };
    float* dinv  = (float*)alloc(N_NODES * 4);
    int*   cnt   = (int*)alloc(N_NODES * 4);
    int*   off   = (int*)alloc((N_NODES + 1) * 4);
    int*   fill  = (int*)alloc(N_NODES * 4);
    int*   srow  = (int*)alloc(N_EDGES * 4);
    float* snorm = (float*)alloc(N_EDGES * 4);
    unsigned short* x0b  = (unsigned short*)alloc((size_t)N_NODES * 256 * 2);
    unsigned short* W1t  = (unsigned short*)alloc(256 * 256 * 2);
    unsigned short* W2t  = (unsigned short*)alloc(256 * 256 * 2);
    unsigned short* W3t  = (unsigned short*)alloc(128 * 256 * 2);
    unsigned short* ipwb = (unsigned short*)alloc(768 * 256 * 2);
    unsigned short* opwb = (unsigned short*)alloc(256 * 256 * 2);
    float* ipbs          = (float*)alloc(768 * 4);
    unsigned short* Hb   = (unsigned short*)alloc((size_t)N_NODES * 256 * 2);
    unsigned short* XAb  = (unsigned short*)alloc((size_t)N_NODES * 256 * 2);
    unsigned short* XBb  = (unsigned short*)alloc((size_t)N_NODES * 256 * 2);
    unsigned short* QKVb = (unsigned short*)alloc((size_t)N_NODES * 768 * 2);
    unsigned short* Vt   = (unsigned short*)alloc((size_t)4 * 64 * 4096 * 2);
    unsigned short* Po   = (unsigned short*)alloc((size_t)16 * 4096 * 64 * 2);
    float* Pl            = (float*)alloc((size_t)16 * 4096 * 4);

    const int* row = eix;
    const int* col = eix + N_EDGES;

    // one-time conversions
    conv_bf16<<<1024, 256, 0, stream>>>(x0, x0b, N_NODES * 256);
    conv_ipw<<<192, 256, 0, stream>>>(ipw, ipwb);
    conv_bf16<<<64, 256, 0, stream>>>(opw, opwb, 256 * 256);
    scale_ipb<<<1, 768, 0, stream>>>(ipb, ipbs);
    transpose_w<<<dim3(8, 8), dim3(32, 8), 0, stream>>>(W1, W1t, 256);
    transpose_w<<<dim3(8, 8), dim3(32, 8), 0, stream>>>(W2, W2t, 256);
    transpose_w<<<dim3(4, 8), dim3(32, 8), 0, stream>>>(W3, W3t, 128);

    // graph preprocessing (shared by all 3 GCN layers)
    init_deg_cnt<<<16, 256, 0, stream>>>(dinv, cnt);
    deg_accum<<<512, 256, 0, stream>>>(col, ew, dinv, cnt);
    finalize_dinv<<<16, 256, 0, stream>>>(dinv);
    scan_offsets<<<1, 1024, 0, stream>>>(cnt, off, fill);
    scatter_edges<<<512, 256, 0, stream>>>(row, col, ew, dinv, fill, srow, snorm);

    // GCN layer 1
    gemm_bf16<false, 0><<<dim3(4, 256), 64, 0, stream>>>(x0b, W1t, nullptr, Hb, 256);
    gcn_agg<256, false><<<N_NODES, 256, 0, stream>>>(Hb, off, srow, snorm, dinv, b1, XAb, nullptr);
    // MHA 1 (+relu)
    gemm_bf16<true, 0><<<dim3(12, 256), 64, 0, stream>>>(XAb, ipwb, ipbs, QKVb, 768);
    prep_v<<<dim3(64, 4), 256, 0, stream>>>(QKVb, Vt);
    attn_mfma<<<dim3(64, 4, 4), 256, 0, stream>>>(QKVb, Vt, Po, Pl);
    attn_combine<<<N_NODES, 256, 0, stream>>>(Po, Pl, Hb);
    gemm_bf16<true, 1><<<dim3(4, 256), 64, 0, stream>>>(Hb, opwb, opb, XBb, 256);
    // GCN layer 2
    gemm_bf16<false, 0><<<dim3(4, 256), 64, 0, stream>>>(XBb, W2t, nullptr, Hb, 256);
    gcn_agg<256, false><<<N_NODES, 256, 0, stream>>>(Hb, off, srow, snorm, dinv, b2, XAb, nullptr);
    // MHA 2 (+relu)
    gemm_bf16<true, 0><<<dim3(12, 256), 64, 0, stream>>>(XAb, ipwb, ipbs, QKVb, 768);
    prep_v<<<dim3(64, 4), 256, 0, stream>>>(QKVb, Vt);
    attn_mfma<<<dim3(64, 4, 4), 256, 0, stream>>>(QKVb, Vt, Po, Pl);
    attn_combine<<<N_NODES, 256, 0, stream>>>(Po, Pl, Hb);
    gemm_bf16<true, 1><<<dim3(4, 256), 64, 0, stream>>>(Hb, opwb, opb, XBb, 256);
    // GCN layer 3 (+sigmoid) -> d_out
    gemm_bf16<false, 0><<<dim3(2, 256), 64, 0, stream>>>(XBb, W3t, nullptr, Hb, 128);
    gcn_agg<128, true><<<N_NODES, 128, 0, stream>>>(Hb, off, srow, snorm, dinv, b3, nullptr, out);
}

// Round 6
// 309.653 us; speedup vs baseline: 8.6873x; 1.1462x over previous
//
#include <hip/hip_runtime.h>
#include <math.h>

#define N_NODES 4096
#define N_EDGES 262144

typedef __attribute__((ext_vector_type(4))) float f32x4;
typedef __attribute__((ext_vector_type(8))) short s16x8;
typedef __attribute__((ext_vector_type(4))) unsigned short u16x4;

__device__ inline unsigned short f2bf(float f) {
    unsigned u = __builtin_bit_cast(unsigned, f);
    u += 0x7FFF + ((u >> 16) & 1);  // RNE
    return (unsigned short)(u >> 16);
}
__device__ inline float bf2f(unsigned short u) {
    unsigned x = ((unsigned)u) << 16;
    return __builtin_bit_cast(float, x);
}

// T2 XOR swizzle for 128-byte LDS rows
#define SWZ(row, colb) (((row) << 7) + ((colb) ^ (((row) & 7) << 4)))

// ---------------------------------------------------------------------------
// One fused prep kernel: x0->bf16, ipw(+K scale)->bf16, opw->bf16,
// W1/W2/W3 transpose->bf16, ipb scale, deg/cnt init.
// ---------------------------------------------------------------------------
__global__ void prep_all(const float* __restrict__ x0, const float* __restrict__ ipw,
                         const float* __restrict__ opw, const float* __restrict__ ipb,
                         const float* __restrict__ W1, const float* __restrict__ W2,
                         const float* __restrict__ W3,
                         unsigned short* __restrict__ x0b, unsigned short* __restrict__ ipwb,
                         unsigned short* __restrict__ opwb, float* __restrict__ ipbs,
                         unsigned short* __restrict__ W1t, unsigned short* __restrict__ W2t,
                         unsigned short* __restrict__ W3t,
                         float* __restrict__ deg, int* __restrict__ cnt) {
    const int NA = 262144;   // x0 vec4
    const int NB = 49152;    // ipw vec4
    const int NC = 16384;    // opw vec4
    const int ND1 = 65536, ND2 = 65536, ND3 = 32768;  // transposes (scalar)
    const int NE = 768, NF = 4096;
    const int total = NA + NB + NC + ND1 + ND2 + ND3 + NE + NF;
    for (int idx = blockIdx.x * blockDim.x + threadIdx.x; idx < total;
         idx += gridDim.x * blockDim.x) {
        int t = idx;
        if (t < NA) {
            int i = t * 4;
            f32x4 v = *(const f32x4*)(x0 + i);
            u16x4 o;
#pragma unroll
            for (int j = 0; j < 4; j++) o[j] = f2bf(v[j]);
            *(u16x4*)(x0b + i) = o;
            continue;
        }
        t -= NA;
        if (t < NB) {
            int i = t * 4;
            int r = i >> 8;
            float sc = (r >= 256 && r < 512) ? 0.1803369f : 1.0f;  // 0.125*log2(e)
            f32x4 v = *(const f32x4*)(ipw + i);
            u16x4 o;
#pragma unroll
            for (int j = 0; j < 4; j++) o[j] = f2bf(v[j] * sc);
            *(u16x4*)(ipwb + i) = o;
            continue;
        }
        t -= NB;
        if (t < NC) {
            int i = t * 4;
            f32x4 v = *(const f32x4*)(opw + i);
            u16x4 o;
#pragma unroll
            for (int j = 0; j < 4; j++) o[j] = f2bf(v[j]);
            *(u16x4*)(opwb + i) = o;
            continue;
        }
        t -= NC;
        if (t < ND1) {
            int r = t & 255, c = t >> 8;
            W1t[c * 256 + r] = f2bf(W1[r * 256 + c]);
            continue;
        }
        t -= ND1;
        if (t < ND2) {
            int r = t & 255, c = t >> 8;
            W2t[c * 256 + r] = f2bf(W2[r * 256 + c]);
            continue;
        }
        t -= ND2;
        if (t < ND3) {
            int r = t & 255, c = t >> 8;   // c in 0..127
            W3t[c * 256 + r] = f2bf(W3[r * 128 + c]);
            continue;
        }
        t -= ND3;
        if (t < NE) {
            float sc = (t >= 256 && t < 512) ? 0.1803369f : 1.0f;
            ipbs[t] = ipb[t] * sc;
            continue;
        }
        t -= NE;
        deg[t] = 1.0f;  // self-loop weight
        cnt[t] = 0;
    }
}

// ---------------------------------------------------------------------------
// Graph preprocessing
// ---------------------------------------------------------------------------
__global__ void deg_accum(const int* __restrict__ col, const float* __restrict__ ew,
                          float* deg, int* cnt) {
    for (int e = blockIdx.x * blockDim.x + threadIdx.x; e < N_EDGES;
         e += gridDim.x * blockDim.x) {
        int c = col[e];
        atomicAdd(&deg[c], ew[e]);
        atomicAdd(&cnt[c], 1);
    }
}

// dinv (in-place on deg) + exclusive scan of cnt -> off/fill
__global__ __launch_bounds__(1024) void scan_offsets(const int* __restrict__ cnt,
                                                     float* __restrict__ deg,
                                                     int* off, int* fill) {
    __shared__ int s[1024];
    int tid = threadIdx.x;
#pragma unroll
    for (int q = 0; q < 4; q++) {
        int i = tid * 4 + q;
        float d = deg[i];
        deg[i] = d > 0.f ? rsqrtf(d) : 0.f;
    }
    int c0 = cnt[tid * 4 + 0], c1 = cnt[tid * 4 + 1];
    int c2 = cnt[tid * 4 + 2], c3 = cnt[tid * 4 + 3];
    int lsum = c0 + c1 + c2 + c3;
    s[tid] = lsum;
    __syncthreads();
    for (int d = 1; d < 1024; d <<= 1) {
        int v = (tid >= d) ? s[tid - d] : 0;
        __syncthreads();
        s[tid] += v;
        __syncthreads();
    }
    int incl = s[tid];
    int base = incl - lsum;
    int o0 = base, o1 = base + c0, o2 = base + c0 + c1, o3 = base + c0 + c1 + c2;
    off[tid * 4 + 0] = o0;  fill[tid * 4 + 0] = o0;
    off[tid * 4 + 1] = o1;  fill[tid * 4 + 1] = o1;
    off[tid * 4 + 2] = o2;  fill[tid * 4 + 2] = o2;
    off[tid * 4 + 3] = o3;  fill[tid * 4 + 3] = o3;
    if (tid == 1023) off[4096] = incl;
}

__global__ void scatter_edges(const int* __restrict__ row, const int* __restrict__ col,
                              const float* __restrict__ ew, const float* __restrict__ dinv,
                              int* fill, int* srow, float* snorm) {
    for (int e = blockIdx.x * blockDim.x + threadIdx.x; e < N_EDGES;
         e += gridDim.x * blockDim.x) {
        int r = row[e], c = col[e];
        int p = atomicAdd(&fill[c], 1);
        srow[p] = r;
        snorm[p] = dinv[r] * ew[e] * dinv[c];
    }
}

// ---------------------------------------------------------------------------
// Single-wave bf16 GEMM: 32x64 tile/wave. C = A[N][256] @ B^T (B [P][256] bf16)
// QKV=true: blocks with bcol>=512 are V columns -> write transposed Vt
// [head][d][n] directly (8B stores) and skip the C store.
// grid (P/64, N/32), 64 threads.
// ---------------------------------------------------------------------------
template <bool BIAS, int ACT, bool QKV>
__global__ __launch_bounds__(64) void gemm_bf16(const unsigned short* __restrict__ A,
                                                const unsigned short* __restrict__ B,
                                                const float* __restrict__ bias,
                                                unsigned short* __restrict__ C,
                                                unsigned short* __restrict__ Vt, int P) {
    int lane = threadIdx.x & 63;
    int lx = lane & 15, g = lane >> 4;
    int brow = blockIdx.y * 32, bcol = blockIdx.x * 64;
    const unsigned short* Ap0 = A + (size_t)(brow + lx) * 256 + g * 8;
    const unsigned short* Ap1 = Ap0 + 16 * 256;
    const unsigned short* Bp = B + (size_t)(bcol + lx) * 256 + g * 8;
    f32x4 acc[2][4];
#pragma unroll
    for (int mi = 0; mi < 2; mi++)
#pragma unroll
        for (int nt = 0; nt < 4; nt++) acc[mi][nt] = f32x4{0.f, 0.f, 0.f, 0.f};
#pragma unroll
    for (int kc = 0; kc < 8; kc++) {
        s16x8 a0 = *(const s16x8*)(Ap0 + kc * 32);
        s16x8 a1 = *(const s16x8*)(Ap1 + kc * 32);
#pragma unroll
        for (int nt = 0; nt < 4; nt++) {
            s16x8 b = *(const s16x8*)(Bp + (size_t)nt * 16 * 256 + kc * 32);
            acc[0][nt] = __builtin_amdgcn_mfma_f32_16x16x32_bf16(a0, b, acc[0][nt], 0, 0, 0);
            acc[1][nt] = __builtin_amdgcn_mfma_f32_16x16x32_bf16(a1, b, acc[1][nt], 0, 0, 0);
        }
    }
    bool isV = QKV && (bcol >= 512);
    if (!isV) {
#pragma unroll
        for (int mi = 0; mi < 2; mi++)
#pragma unroll
            for (int nt = 0; nt < 4; nt++)
#pragma unroll
                for (int r = 0; r < 4; r++) {
                    int row = brow + mi * 16 + g * 4 + r, col = bcol + nt * 16 + lx;
                    float v = acc[mi][nt][r];
                    if (BIAS) v += bias[col];
                    if (ACT == 1) v = fmaxf(v, 0.f);
                    C[(size_t)row * P + col] = f2bf(v);
                }
    } else {
        int head = (bcol - 512) >> 6;
#pragma unroll
        for (int mi = 0; mi < 2; mi++)
#pragma unroll
            for (int nt = 0; nt < 4; nt++) {
                int col = bcol + nt * 16 + lx;
                u16x4 vv;
#pragma unroll
                for (int r = 0; r < 4; r++) {
                    float v = acc[mi][nt][r];
                    if (BIAS) v += bias[col];
                    vv[r] = f2bf(v);
                }
                *(u16x4*)(Vt + (size_t)(head * 64 + nt * 16 + lx) * 4096 +
                          brow + mi * 16 + g * 4) = vv;
            }
    }
}

// ---------------------------------------------------------------------------
// GCN aggregation: 1 wave per node, vector gathers (u16x4 / uint per thread).
// out[i] = sum norm*H[row] + dinv[i]^2*H[i] + bias
// ---------------------------------------------------------------------------
template <int P, bool SIG>
__global__ __launch_bounds__(64) void gcn_agg(const unsigned short* __restrict__ H,
                                              const int* __restrict__ off,
                                              const int* __restrict__ srow,
                                              const float* __restrict__ snorm,
                                              const float* __restrict__ dinv,
                                              const float* __restrict__ bias,
                                              unsigned short* __restrict__ outb,
                                              float* __restrict__ outf) {
    constexpr int CPT = P / 64;  // cols per thread (4 or 2)
    __shared__ int sr[64];
    __shared__ float sw[64];
    int i = blockIdx.x, tid = threadIdx.x;
    float di = dinv[i];
    float d2 = di * di;
    float acc[CPT];
    if (CPT == 4) {
        u16x4 h = *(const u16x4*)(H + (size_t)i * P + tid * 4);
#pragma unroll
        for (int j = 0; j < 4; j++) acc[j] = d2 * bf2f(h[j]);
    } else {
        unsigned h = *(const unsigned*)(H + (size_t)i * P + tid * 2);
        acc[0] = d2 * bf2f((unsigned short)(h & 0xFFFF));
        acc[1] = d2 * bf2f((unsigned short)(h >> 16));
    }
    int beg = off[i], end = off[i + 1];
    for (int base = beg; base < end; base += 64) {
        int n = min(64, end - base);
        __syncthreads();
        if (tid < n) { sr[tid] = srow[base + tid]; sw[tid] = snorm[base + tid]; }
        __syncthreads();
#pragma unroll 4
        for (int j = 0; j < n; j++) {
            float w = sw[j];
            size_t rb = (size_t)sr[j] * P;
            if (CPT == 4) {
                u16x4 h = *(const u16x4*)(H + rb + tid * 4);
#pragma unroll
                for (int q = 0; q < 4; q++) acc[q] += w * bf2f(h[q]);
            } else {
                unsigned h = *(const unsigned*)(H + rb + tid * 2);
                acc[0] += w * bf2f((unsigned short)(h & 0xFFFF));
                acc[1] += w * bf2f((unsigned short)(h >> 16));
            }
        }
    }
#pragma unroll
    for (int j = 0; j < CPT; j++) {
        int c = tid * CPT + j;
        float v = acc[j] + bias[c];
        if (SIG) {
            v = 1.f / (1.f + exp2f(-v * 1.442695f));
            outf[(size_t)i * P + c] = v;
        } else {
            outb[(size_t)i * P + c] = f2bf(v);
        }
    }
}

// ---------------------------------------------------------------------------
// MFMA flash attention, fixed-base exp2 softmax, double-buffered K/V,
// 8 KV chunks (grid 2048 blocks for occupancy).
// ---------------------------------------------------------------------------
__global__ __launch_bounds__(256) void attn_mfma(const unsigned short* __restrict__ qkv,
                                                 const unsigned short* __restrict__ Vt,
                                                 unsigned short* __restrict__ Po,
                                                 float* __restrict__ Pl) {
    __shared__ unsigned short Ks[2][64 * 64];
    __shared__ unsigned short Vs[2][64 * 64];
    __shared__ unsigned short Ps[4][16 * 64];

    int tid = threadIdx.x;
    int wid = tid >> 6, lane = tid & 63, g = lane >> 4, lx = lane & 15;
    int head = blockIdx.y, chunk = blockIdx.z;
    int qw = blockIdx.x * 64 + wid * 16;

    s16x8 qa[2];
#pragma unroll
    for (int kc = 0; kc < 2; kc++)
        qa[kc] = *(const s16x8*)(qkv + (size_t)(qw + lx) * 768 + head * 64 + kc * 32 + g * 8);

    const unsigned short* Kg = qkv + 256 + head * 64;
    const unsigned short* VtH = Vt + (size_t)head * 64 * 4096;

    int kr0 = tid >> 3, dc0 = tid & 7;
    int kr1 = kr0 + 32;
    s16x8 stK[2], stV[2];
    auto issue = [&](int kt) {
        stK[0] = *(const s16x8*)(Kg + (size_t)(kt * 64 + kr0) * 768 + dc0 * 8);
        stK[1] = *(const s16x8*)(Kg + (size_t)(kt * 64 + kr1) * 768 + dc0 * 8);
        stV[0] = *(const s16x8*)(VtH + (size_t)kr0 * 4096 + kt * 64 + dc0 * 8);
        stV[1] = *(const s16x8*)(VtH + (size_t)kr1 * 4096 + kt * 64 + dc0 * 8);
    };
    auto commit = [&](int b) {
        *(s16x8*)((char*)Ks[b] + SWZ(kr0, dc0 * 16)) = stK[0];
        *(s16x8*)((char*)Ks[b] + SWZ(kr1, dc0 * 16)) = stK[1];
        *(s16x8*)((char*)Vs[b] + SWZ(kr0, dc0 * 16)) = stV[0];
        *(s16x8*)((char*)Vs[b] + SWZ(kr1, dc0 * 16)) = stV[1];
    };

    float lreg[4] = {0.f, 0.f, 0.f, 0.f};
    f32x4 o[4];
#pragma unroll
    for (int dt = 0; dt < 4; dt++) o[dt] = f32x4{0.f, 0.f, 0.f, 0.f};

    char* PsW = (char*)Ps[wid];

    int kt_beg = chunk * 8, kt_end = kt_beg + 8;
    issue(kt_beg);
    commit(0);
    __syncthreads();

    for (int kt = kt_beg; kt < kt_end; kt++) {
        int cur = (kt - kt_beg) & 1;
        if (kt + 1 < kt_end) issue(kt + 1);

        f32x4 s4[4];
        __builtin_amdgcn_s_setprio(1);
#pragma unroll
        for (int nt = 0; nt < 4; nt++) {
            f32x4 acc = f32x4{0.f, 0.f, 0.f, 0.f};
#pragma unroll
            for (int kc = 0; kc < 2; kc++) {
                s16x8 kb = *(const s16x8*)((char*)Ks[cur] + SWZ(nt * 16 + lx, kc * 64 + g * 16));
                acc = __builtin_amdgcn_mfma_f32_16x16x32_bf16(qa[kc], kb, acc, 0, 0, 0);
            }
            s4[nt] = acc;
        }
        __builtin_amdgcn_s_setprio(0);

        // fixed-base softmax: P = exp2(min(s,60)); per-lane l accumulation
#pragma unroll
        for (int nt = 0; nt < 4; nt++)
#pragma unroll
            for (int r = 0; r < 4; r++) {
                float p = exp2f(fminf(s4[nt][r], 60.f));
                lreg[r] += p;
                *(unsigned short*)(PsW + SWZ(4 * g + r, (nt * 16 + lx) * 2)) = f2bf(p);
            }

        __builtin_amdgcn_s_setprio(1);
#pragma unroll
        for (int kc = 0; kc < 2; kc++) {
            s16x8 pa = *(const s16x8*)(PsW + SWZ(lx, kc * 64 + g * 16));
#pragma unroll
            for (int dt = 0; dt < 4; dt++) {
                s16x8 vb = *(const s16x8*)((char*)Vs[cur] + SWZ(dt * 16 + lx, kc * 64 + g * 16));
                o[dt] = __builtin_amdgcn_mfma_f32_16x16x32_bf16(pa, vb, o[dt], 0, 0, 0);
            }
        }
        __builtin_amdgcn_s_setprio(0);

        if (kt + 1 < kt_end) commit(1 - cur);
        __syncthreads();
    }

#pragma unroll
    for (int r = 0; r < 4; r++) {
        float ls = lreg[r];
        ls += __shfl_xor(ls, 1, 16);
        ls += __shfl_xor(ls, 2, 16);
        ls += __shfl_xor(ls, 4, 16);
        ls += __shfl_xor(ls, 8, 16);
        int qrow = qw + 4 * g + r;
        size_t base = (size_t)(chunk * 4 + head) * 4096 + qrow;
        if (lx == 0) Pl[base] = ls;
#pragma unroll
        for (int dt = 0; dt < 4; dt++)
            Po[base * 64 + dt * 16 + lx] = f2bf(o[dt][r]);
    }
}

// ---------------------------------------------------------------------------
// Combine 8 chunk-partials -> att bf16 [N][256]
// ---------------------------------------------------------------------------
__global__ __launch_bounds__(256) void attn_combine(const unsigned short* __restrict__ Po,
                                                    const float* __restrict__ Pl,
                                                    unsigned short* __restrict__ att) {
    int q = blockIdx.x;
    int head = threadIdx.x >> 6, d = threadIdx.x & 63;
    float L = 0.f, ov = 0.f;
#pragma unroll
    for (int c = 0; c < 8; c++) {
        size_t base = (size_t)(c * 4 + head) * 4096 + q;
        L += Pl[base];
        ov += bf2f(Po[base * 64 + d]);
    }
    att[(size_t)q * 256 + head * 64 + d] = f2bf(ov / L);
}

// ---------------------------------------------------------------------------
extern "C" void kernel_launch(void* const* d_in, const int* in_sizes, int n_in,
                              void* d_out, int out_size, void* d_ws, size_t ws_size,
                              hipStream_t stream) {
    const float* x0  = (const float*)d_in[0];
    const int*   eix = (const int*)d_in[1];
    const float* ew  = (const float*)d_in[2];
    const float* W1  = (const float*)d_in[3];
    const float* b1  = (const float*)d_in[4];
    const float* W2  = (const float*)d_in[5];
    const float* b2  = (const float*)d_in[6];
    const float* W3  = (const float*)d_in[7];
    const float* b3  = (const float*)d_in[8];
    const float* ipw = (const float*)d_in[9];
    const float* ipb = (const float*)d_in[10];
    const float* opw = (const float*)d_in[11];
    const float* opb = (const float*)d_in[12];
    float* out = (float*)d_out;

    char* ws = (char*)d_ws;
    size_t o = 0;
    auto alloc = [&](size_t bytes) -> void* {
        void* p = ws + o;
        o = (o + bytes + 255) & ~size_t(255);
        return p;
    };
    float* dinv  = (float*)alloc(N_NODES * 4);   // deg -> dinv in place
    int*   cnt   = (int*)alloc(N_NODES * 4);
    int*   off   = (int*)alloc((N_NODES + 1) * 4);
    int*   fill  = (int*)alloc(N_NODES * 4);
    int*   srow  = (int*)alloc(N_EDGES * 4);
    float* snorm = (float*)alloc(N_EDGES * 4);
    unsigned short* x0b  = (unsigned short*)alloc((size_t)N_NODES * 256 * 2);
    unsigned short* W1t  = (unsigned short*)alloc(256 * 256 * 2);
    unsigned short* W2t  = (unsigned short*)alloc(256 * 256 * 2);
    unsigned short* W3t  = (unsigned short*)alloc(128 * 256 * 2);
    unsigned short* ipwb = (unsigned short*)alloc(768 * 256 * 2);
    unsigned short* opwb = (unsigned short*)alloc(256 * 256 * 2);
    float* ipbs          = (float*)alloc(768 * 4);
    unsigned short* Hb   = (unsigned short*)alloc((size_t)N_NODES * 256 * 2);
    unsigned short* XAb  = (unsigned short*)alloc((size_t)N_NODES * 256 * 2);
    unsigned short* XBb  = (unsigned short*)alloc((size_t)N_NODES * 256 * 2);
    unsigned short* QKVb = (unsigned short*)alloc((size_t)N_NODES * 768 * 2);
    unsigned short* Vt   = (unsigned short*)alloc((size_t)4 * 64 * 4096 * 2);
    unsigned short* Po   = (unsigned short*)alloc((size_t)32 * 4096 * 64 * 2);
    float* Pl            = (float*)alloc((size_t)32 * 4096 * 4);

    const int* row = eix;
    const int* col = eix + N_EDGES;

    prep_all<<<1024, 256, 0, stream>>>(x0, ipw, opw, ipb, W1, W2, W3,
                                       x0b, ipwb, opwb, ipbs, W1t, W2t, W3t, dinv, cnt);
    deg_accum<<<512, 256, 0, stream>>>(col, ew, dinv, cnt);
    scan_offsets<<<1, 1024, 0, stream>>>(cnt, dinv, off, fill);
    scatter_edges<<<512, 256, 0, stream>>>(row, col, ew, dinv, fill, srow, snorm);

    // GCN layer 1
    gemm_bf16<false, 0, false><<<dim3(4, 128), 64, 0, stream>>>(x0b, W1t, nullptr, Hb, nullptr, 256);
    gcn_agg<256, false><<<N_NODES, 64, 0, stream>>>(Hb, off, srow, snorm, dinv, b1, XAb, nullptr);
    // MHA 1 (+relu)
    gemm_bf16<true, 0, true><<<dim3(12, 128), 64, 0, stream>>>(XAb, ipwb, ipbs, QKVb, Vt, 768);
    attn_mfma<<<dim3(64, 4, 8), 256, 0, stream>>>(QKVb, Vt, Po, Pl);
    attn_combine<<<N_NODES, 256, 0, stream>>>(Po, Pl, Hb);
    gemm_bf16<true, 1, false><<<dim3(4, 128), 64, 0, stream>>>(Hb, opwb, opb, XBb, nullptr, 256);
    // GCN layer 2
    gemm_bf16<false, 0, false><<<dim3(4, 128), 64, 0, stream>>>(XBb, W2t, nullptr, Hb, nullptr, 256);
    gcn_agg<256, false><<<N_NODES, 64, 0, stream>>>(Hb, off, srow, snorm, dinv, b2, XAb, nullptr);
    // MHA 2 (+relu)
    gemm_bf16<true, 0, true><<<dim3(12, 128), 64, 0, stream>>>(XAb, ipwb, ipbs, QKVb, Vt, 768);
    attn_mfma<<<dim3(64, 4, 8), 256, 0, stream>>>(QKVb, Vt, Po, Pl);
    attn_combine<<<N_NODES, 256, 0, stream>>>(Po, Pl, Hb);
    gemm_bf16<true, 1, false><<<dim3(4, 128), 64, 0, stream>>>(Hb, opwb, opb, XBb, nullptr, 256);
    // GCN layer 3 (+sigmoid) -> d_out
    gemm_bf16<false, 0, false><<<dim3(2, 128), 64, 0, stream>>>(XBb, W3t, nullptr, Hb, nullptr, 128);
    gcn_agg<128, true><<<N_NODES, 64, 0, stream>>>(Hb, off, srow, snorm, dinv, b3, nullptr, out);
}

// Round 7
// 303.804 us; speedup vs baseline: 8.8546x; 1.0193x over previous
//
#include <hip/hip_runtime.h>
#include <math.h>

#define N_NODES 4096
#define N_EDGES 262144

typedef __attribute__((ext_vector_type(4))) float f32x4;
typedef __attribute__((ext_vector_type(8))) short s16x8;
typedef __attribute__((ext_vector_type(4))) unsigned short u16x4;

__device__ inline unsigned short f2bf(float f) {
    unsigned u = __builtin_bit_cast(unsigned, f);
    u += 0x7FFF + ((u >> 16) & 1);  // RNE
    return (unsigned short)(u >> 16);
}
__device__ inline unsigned short f2bf_t(float f) {  // truncate (1 op)
    return (unsigned short)(__builtin_bit_cast(unsigned, f) >> 16);
}
__device__ inline float bf2f(unsigned short u) {
    unsigned x = ((unsigned)u) << 16;
    return __builtin_bit_cast(float, x);
}

// T2 XOR swizzle for 128-byte LDS rows
#define SWZ(row, colb) (((row) << 7) + ((colb) ^ (((row) & 7) << 4)))

// ---------------------------------------------------------------------------
// Fused prep: x0->bf16, ipw(+K scale)->bf16, opw->bf16, W1/W2/W3 T->bf16, ipb
// ---------------------------------------------------------------------------
__global__ void prep_all(const float* __restrict__ x0, const float* __restrict__ ipw,
                         const float* __restrict__ opw, const float* __restrict__ ipb,
                         const float* __restrict__ W1, const float* __restrict__ W2,
                         const float* __restrict__ W3,
                         unsigned short* __restrict__ x0b, unsigned short* __restrict__ ipwb,
                         unsigned short* __restrict__ opwb, float* __restrict__ ipbs,
                         unsigned short* __restrict__ W1t, unsigned short* __restrict__ W2t,
                         unsigned short* __restrict__ W3t) {
    const int NA = 262144;   // x0 vec4
    const int NB = 49152;    // ipw vec4
    const int NC = 16384;    // opw vec4
    const int ND1 = 65536, ND2 = 65536, ND3 = 32768;  // transposes (scalar)
    const int NE = 768;
    const int total = NA + NB + NC + ND1 + ND2 + ND3 + NE;
    for (int idx = blockIdx.x * blockDim.x + threadIdx.x; idx < total;
         idx += gridDim.x * blockDim.x) {
        int t = idx;
        if (t < NA) {
            int i = t * 4;
            f32x4 v = *(const f32x4*)(x0 + i);
            u16x4 o;
#pragma unroll
            for (int j = 0; j < 4; j++) o[j] = f2bf(v[j]);
            *(u16x4*)(x0b + i) = o;
            continue;
        }
        t -= NA;
        if (t < NB) {
            int i = t * 4;
            int r = i >> 8;
            float sc = (r >= 256 && r < 512) ? 0.1803369f : 1.0f;  // 0.125*log2(e)
            f32x4 v = *(const f32x4*)(ipw + i);
            u16x4 o;
#pragma unroll
            for (int j = 0; j < 4; j++) o[j] = f2bf(v[j] * sc);
            *(u16x4*)(ipwb + i) = o;
            continue;
        }
        t -= NB;
        if (t < NC) {
            int i = t * 4;
            f32x4 v = *(const f32x4*)(opw + i);
            u16x4 o;
#pragma unroll
            for (int j = 0; j < 4; j++) o[j] = f2bf(v[j]);
            *(u16x4*)(opwb + i) = o;
            continue;
        }
        t -= NC;
        if (t < ND1) {
            int r = t & 255, c = t >> 8;
            W1t[c * 256 + r] = f2bf(W1[r * 256 + c]);
            continue;
        }
        t -= ND1;
        if (t < ND2) {
            int r = t & 255, c = t >> 8;
            W2t[c * 256 + r] = f2bf(W2[r * 256 + c]);
            continue;
        }
        t -= ND2;
        if (t < ND3) {
            int r = t & 255, c = t >> 8;   // c in 0..127
            W3t[c * 256 + r] = f2bf(W3[r * 128 + c]);
            continue;
        }
        t -= ND3;
        {
            float sc = (t >= 256 && t < 512) ? 0.1803369f : 1.0f;
            ipbs[t] = ipb[t] * sc;
        }
    }
}

// ---------------------------------------------------------------------------
// Graph preprocessing (deg/cnt zeroed by hipMemsetAsync)
// ---------------------------------------------------------------------------
__global__ void deg_accum(const int* __restrict__ col, const float* __restrict__ ew,
                          float* deg, int* cnt) {
    for (int e = blockIdx.x * blockDim.x + threadIdx.x; e < N_EDGES;
         e += gridDim.x * blockDim.x) {
        int c = col[e];
        atomicAdd(&deg[c], ew[e]);
        atomicAdd(&cnt[c], 1);
    }
}

// dinv = rsqrt(deg + 1)  (self-loop weight folded in) + exclusive scan of cnt
__global__ __launch_bounds__(1024) void scan_offsets(const int* __restrict__ cnt,
                                                     float* __restrict__ deg,
                                                     int* off, int* fill) {
    __shared__ int s[1024];
    int tid = threadIdx.x;
#pragma unroll
    for (int q = 0; q < 4; q++) {
        int i = tid * 4 + q;
        deg[i] = rsqrtf(deg[i] + 1.0f);
    }
    int c0 = cnt[tid * 4 + 0], c1 = cnt[tid * 4 + 1];
    int c2 = cnt[tid * 4 + 2], c3 = cnt[tid * 4 + 3];
    int lsum = c0 + c1 + c2 + c3;
    s[tid] = lsum;
    __syncthreads();
    for (int d = 1; d < 1024; d <<= 1) {
        int v = (tid >= d) ? s[tid - d] : 0;
        __syncthreads();
        s[tid] += v;
        __syncthreads();
    }
    int incl = s[tid];
    int base = incl - lsum;
    int o0 = base, o1 = base + c0, o2 = base + c0 + c1, o3 = base + c0 + c1 + c2;
    off[tid * 4 + 0] = o0;  fill[tid * 4 + 0] = o0;
    off[tid * 4 + 1] = o1;  fill[tid * 4 + 1] = o1;
    off[tid * 4 + 2] = o2;  fill[tid * 4 + 2] = o2;
    off[tid * 4 + 3] = o3;  fill[tid * 4 + 3] = o3;
    if (tid == 1023) off[4096] = incl;
}

// pack {row, norm} into one u64 per edge
__global__ void scatter_edges(const int* __restrict__ row, const int* __restrict__ col,
                              const float* __restrict__ ew, const float* __restrict__ dinv,
                              int* fill, unsigned long long* __restrict__ ep) {
    for (int e = blockIdx.x * blockDim.x + threadIdx.x; e < N_EDGES;
         e += gridDim.x * blockDim.x) {
        int r = row[e], c = col[e];
        int p = atomicAdd(&fill[c], 1);
        float w = dinv[r] * ew[e] * dinv[c];
        unsigned long long v =
            ((unsigned long long)__builtin_bit_cast(unsigned, w) << 32) | (unsigned)r;
        ep[p] = v;
    }
}

// ---------------------------------------------------------------------------
// Single-wave bf16 GEMM: 32x64 tile/wave. C = A[N][256] @ B^T (B [P][256] bf16)
// QKV=true: bcol>=512 blocks write transposed Vt [head][d][n] directly.
// ---------------------------------------------------------------------------
template <bool BIAS, int ACT, bool QKV>
__global__ __launch_bounds__(64) void gemm_bf16(const unsigned short* __restrict__ A,
                                                const unsigned short* __restrict__ B,
                                                const float* __restrict__ bias,
                                                unsigned short* __restrict__ C,
                                                unsigned short* __restrict__ Vt, int P) {
    int lane = threadIdx.x & 63;
    int lx = lane & 15, g = lane >> 4;
    int brow = blockIdx.y * 32, bcol = blockIdx.x * 64;
    const unsigned short* Ap0 = A + (size_t)(brow + lx) * 256 + g * 8;
    const unsigned short* Ap1 = Ap0 + 16 * 256;
    const unsigned short* Bp = B + (size_t)(bcol + lx) * 256 + g * 8;
    f32x4 acc[2][4];
#pragma unroll
    for (int mi = 0; mi < 2; mi++)
#pragma unroll
        for (int nt = 0; nt < 4; nt++) acc[mi][nt] = f32x4{0.f, 0.f, 0.f, 0.f};
#pragma unroll
    for (int kc = 0; kc < 8; kc++) {
        s16x8 a0 = *(const s16x8*)(Ap0 + kc * 32);
        s16x8 a1 = *(const s16x8*)(Ap1 + kc * 32);
#pragma unroll
        for (int nt = 0; nt < 4; nt++) {
            s16x8 b = *(const s16x8*)(Bp + (size_t)nt * 16 * 256 + kc * 32);
            acc[0][nt] = __builtin_amdgcn_mfma_f32_16x16x32_bf16(a0, b, acc[0][nt], 0, 0, 0);
            acc[1][nt] = __builtin_amdgcn_mfma_f32_16x16x32_bf16(a1, b, acc[1][nt], 0, 0, 0);
        }
    }
    bool isV = QKV && (bcol >= 512);
    if (!isV) {
#pragma unroll
        for (int mi = 0; mi < 2; mi++)
#pragma unroll
            for (int nt = 0; nt < 4; nt++)
#pragma unroll
                for (int r = 0; r < 4; r++) {
                    int row = brow + mi * 16 + g * 4 + r, col = bcol + nt * 16 + lx;
                    float v = acc[mi][nt][r];
                    if (BIAS) v += bias[col];
                    if (ACT == 1) v = fmaxf(v, 0.f);
                    C[(size_t)row * P + col] = f2bf(v);
                }
    } else {
        int head = (bcol - 512) >> 6;
#pragma unroll
        for (int mi = 0; mi < 2; mi++)
#pragma unroll
            for (int nt = 0; nt < 4; nt++) {
                int col = bcol + nt * 16 + lx;
                u16x4 vv;
#pragma unroll
                for (int r = 0; r < 4; r++) {
                    float v = acc[mi][nt][r];
                    if (BIAS) v += bias[col];
                    vv[r] = f2bf(v);
                }
                *(u16x4*)(Vt + (size_t)(head * 64 + nt * 16 + lx) * 4096 +
                          brow + mi * 16 + g * 4) = vv;
            }
    }
}

// ---------------------------------------------------------------------------
// GCN aggregation: 1 wave per node, packed edge metadata (1 ds_read_b64 / edge)
// ---------------------------------------------------------------------------
template <int P, bool SIG>
__global__ __launch_bounds__(64) void gcn_agg(const unsigned short* __restrict__ H,
                                              const int* __restrict__ off,
                                              const unsigned long long* __restrict__ ep,
                                              const float* __restrict__ dinv,
                                              const float* __restrict__ bias,
                                              unsigned short* __restrict__ outb,
                                              float* __restrict__ outf) {
    constexpr int CPT = P / 64;  // cols per thread (4 or 2)
    __shared__ unsigned long long se[64];
    int i = blockIdx.x, tid = threadIdx.x;
    float di = dinv[i];
    float d2 = di * di;
    float acc[CPT];
    if (CPT == 4) {
        u16x4 h = *(const u16x4*)(H + (size_t)i * P + tid * 4);
#pragma unroll
        for (int j = 0; j < 4; j++) acc[j] = d2 * bf2f(h[j]);
    } else {
        unsigned h = *(const unsigned*)(H + (size_t)i * P + tid * 2);
        acc[0] = d2 * bf2f((unsigned short)(h & 0xFFFF));
        acc[1] = d2 * bf2f((unsigned short)(h >> 16));
    }
    int beg = off[i], end = off[i + 1];
    for (int base = beg; base < end; base += 64) {
        int n = min(64, end - base);
        __syncthreads();
        if (tid < n) se[tid] = ep[base + tid];
        __syncthreads();
#pragma unroll 4
        for (int j = 0; j < n; j++) {
            unsigned long long v = se[j];
            int r = (int)(unsigned)v;
            float w = __builtin_bit_cast(float, (unsigned)(v >> 32));
            size_t rb = (size_t)r * P;
            if (CPT == 4) {
                u16x4 h = *(const u16x4*)(H + rb + tid * 4);
#pragma unroll
                for (int q = 0; q < 4; q++) acc[q] += w * bf2f(h[q]);
            } else {
                unsigned h = *(const unsigned*)(H + rb + tid * 2);
                acc[0] += w * bf2f((unsigned short)(h & 0xFFFF));
                acc[1] += w * bf2f((unsigned short)(h >> 16));
            }
        }
    }
#pragma unroll
    for (int j = 0; j < CPT; j++) {
        int c = tid * CPT + j;
        float v = acc[j] + bias[c];
        if (SIG) {
            v = 1.f / (1.f + exp2f(-v * 1.442695f));
            outf[(size_t)i * P + c] = v;
        } else {
            outb[(size_t)i * P + c] = f2bf(v);
        }
    }
}

// ---------------------------------------------------------------------------
// MFMA flash attention, fixed-base exp2 softmax, double-buffered K/V,
// 4 KV chunks. Pointer-increment staging; truncating P conversion.
// ---------------------------------------------------------------------------
__global__ __launch_bounds__(256) void attn_mfma(const unsigned short* __restrict__ qkv,
                                                 const unsigned short* __restrict__ Vt,
                                                 unsigned short* __restrict__ Po,
                                                 float* __restrict__ Pl) {
    __shared__ unsigned short Ks[2][64 * 64];
    __shared__ unsigned short Vs[2][64 * 64];
    __shared__ unsigned short Ps[4][16 * 64];

    int tid = threadIdx.x;
    int wid = tid >> 6, lane = tid & 63, g = lane >> 4, lx = lane & 15;
    int head = blockIdx.y, chunk = blockIdx.z;
    int qw = blockIdx.x * 64 + wid * 16;

    s16x8 qa[2];
#pragma unroll
    for (int kc = 0; kc < 2; kc++)
        qa[kc] = *(const s16x8*)(qkv + (size_t)(qw + lx) * 768 + head * 64 + kc * 32 + g * 8);

    int kr0 = tid >> 3, dc0 = tid & 7;
    int kr1 = kr0 + 32;
    int kt_beg = chunk * 16, kt_end = kt_beg + 16;

    // staging pointers, advanced by constant strides
    const unsigned short* kp0 =
        qkv + 256 + head * 64 + (size_t)(kt_beg * 64 + kr0) * 768 + dc0 * 8;
    const unsigned short* kp1 = kp0 + (size_t)32 * 768;
    const unsigned short* vp0 =
        Vt + (size_t)head * 64 * 4096 + (size_t)kr0 * 4096 + kt_beg * 64 + dc0 * 8;
    const unsigned short* vp1 = vp0 + (size_t)32 * 4096;

    s16x8 stK[2], stV[2];
    auto issue = [&]() {
        stK[0] = *(const s16x8*)kp0;
        stK[1] = *(const s16x8*)kp1;
        stV[0] = *(const s16x8*)vp0;
        stV[1] = *(const s16x8*)vp1;
        kp0 += 64 * 768; kp1 += 64 * 768;
        vp0 += 64; vp1 += 64;
    };
    auto commit = [&](int b) {
        *(s16x8*)((char*)Ks[b] + SWZ(kr0, dc0 * 16)) = stK[0];
        *(s16x8*)((char*)Ks[b] + SWZ(kr1, dc0 * 16)) = stK[1];
        *(s16x8*)((char*)Vs[b] + SWZ(kr0, dc0 * 16)) = stV[0];
        *(s16x8*)((char*)Vs[b] + SWZ(kr1, dc0 * 16)) = stV[1];
    };

    float lreg[4] = {0.f, 0.f, 0.f, 0.f};
    f32x4 o[4];
#pragma unroll
    for (int dt = 0; dt < 4; dt++) o[dt] = f32x4{0.f, 0.f, 0.f, 0.f};

    char* PsW = (char*)Ps[wid];

    issue();
    commit(0);
    __syncthreads();

    for (int kt = kt_beg; kt < kt_end; kt++) {
        int cur = (kt - kt_beg) & 1;
        if (kt + 1 < kt_end) issue();

        f32x4 s4[4];
        __builtin_amdgcn_s_setprio(1);
#pragma unroll
        for (int nt = 0; nt < 4; nt++) {
            f32x4 acc = f32x4{0.f, 0.f, 0.f, 0.f};
#pragma unroll
            for (int kc = 0; kc < 2; kc++) {
                s16x8 kb = *(const s16x8*)((char*)Ks[cur] + SWZ(nt * 16 + lx, kc * 64 + g * 16));
                acc = __builtin_amdgcn_mfma_f32_16x16x32_bf16(qa[kc], kb, acc, 0, 0, 0);
            }
            s4[nt] = acc;
        }
        __builtin_amdgcn_s_setprio(0);

        // fixed-base softmax: P = exp2(min(s,60)); per-lane l accumulation
#pragma unroll
        for (int nt = 0; nt < 4; nt++)
#pragma unroll
            for (int r = 0; r < 4; r++) {
                float p = exp2f(fminf(s4[nt][r], 60.f));
                lreg[r] += p;
                *(unsigned short*)(PsW + SWZ(4 * g + r, (nt * 16 + lx) * 2)) = f2bf_t(p);
            }

        __builtin_amdgcn_s_setprio(1);
#pragma unroll
        for (int kc = 0; kc < 2; kc++) {
            s16x8 pa = *(const s16x8*)(PsW + SWZ(lx, kc * 64 + g * 16));
#pragma unroll
            for (int dt = 0; dt < 4; dt++) {
                s16x8 vb = *(const s16x8*)((char*)Vs[cur] + SWZ(dt * 16 + lx, kc * 64 + g * 16));
                o[dt] = __builtin_amdgcn_mfma_f32_16x16x32_bf16(pa, vb, o[dt], 0, 0, 0);
            }
        }
        __builtin_amdgcn_s_setprio(0);

        if (kt + 1 < kt_end) commit(1 - cur);
        __syncthreads();
    }

#pragma unroll
    for (int r = 0; r < 4; r++) {
        float ls = lreg[r];
        ls += __shfl_xor(ls, 1, 16);
        ls += __shfl_xor(ls, 2, 16);
        ls += __shfl_xor(ls, 4, 16);
        ls += __shfl_xor(ls, 8, 16);
        int qrow = qw + 4 * g + r;
        size_t base = (size_t)(chunk * 4 + head) * 4096 + qrow;
        if (lx == 0) Pl[base] = ls;
#pragma unroll
        for (int dt = 0; dt < 4; dt++)
            Po[base * 64 + dt * 16 + lx] = f2bf(o[dt][r]);
    }
}

// ---------------------------------------------------------------------------
// Combine 4 chunk-partials -> att bf16 [N][256]. 4 q-rows per block,
// vectorized u16x4 loads/stores.
// ---------------------------------------------------------------------------
__global__ __launch_bounds__(256) void attn_combine(const unsigned short* __restrict__ Po,
                                                    const float* __restrict__ Pl,
                                                    unsigned short* __restrict__ att) {
    int tid = threadIdx.x;
    int q = blockIdx.x * 4 + (tid >> 6);
    int lane = tid & 63;
    int head = lane >> 4, quad = lane & 15;
    float L = 0.f;
    f32x4 ov = {0.f, 0.f, 0.f, 0.f};
#pragma unroll
    for (int c = 0; c < 4; c++) {
        size_t base = (size_t)(c * 4 + head) * 4096 + q;
        L += Pl[base];
        u16x4 p = *(const u16x4*)(Po + base * 64 + quad * 4);
#pragma unroll
        for (int k = 0; k < 4; k++) ov[k] += bf2f(p[k]);
    }
    float inv = 1.0f / L;
    u16x4 r;
#pragma unroll
    for (int k = 0; k < 4; k++) r[k] = f2bf(ov[k] * inv);
    *(u16x4*)(att + (size_t)q * 256 + head * 64 + quad * 4) = r;
}

// ---------------------------------------------------------------------------
extern "C" void kernel_launch(void* const* d_in, const int* in_sizes, int n_in,
                              void* d_out, int out_size, void* d_ws, size_t ws_size,
                              hipStream_t stream) {
    const float* x0  = (const float*)d_in[0];
    const int*   eix = (const int*)d_in[1];
    const float* ew  = (const float*)d_in[2];
    const float* W1  = (const float*)d_in[3];
    const float* b1  = (const float*)d_in[4];
    const float* W2  = (const float*)d_in[5];
    const float* b2  = (const float*)d_in[6];
    const float* W3  = (const float*)d_in[7];
    const float* b3  = (const float*)d_in[8];
    const float* ipw = (const float*)d_in[9];
    const float* ipb = (const float*)d_in[10];
    const float* opw = (const float*)d_in[11];
    const float* opb = (const float*)d_in[12];
    float* out = (float*)d_out;

    char* ws = (char*)d_ws;
    size_t o = 0;
    auto alloc = [&](size_t bytes) -> void* {
        void* p = ws + o;
        o = (o + bytes + 255) & ~size_t(255);
        return p;
    };
    float* dinv  = (float*)alloc(N_NODES * 4);   // deg -> dinv in place
    int*   cnt   = (int*)alloc(N_NODES * 4);
    int*   off   = (int*)alloc((N_NODES + 1) * 4);
    int*   fill  = (int*)alloc(N_NODES * 4);
    unsigned long long* ep = (unsigned long long*)alloc((size_t)N_EDGES * 8);
    unsigned short* x0b  = (unsigned short*)alloc((size_t)N_NODES * 256 * 2);
    unsigned short* W1t  = (unsigned short*)alloc(256 * 256 * 2);
    unsigned short* W2t  = (unsigned short*)alloc(256 * 256 * 2);
    unsigned short* W3t  = (unsigned short*)alloc(128 * 256 * 2);
    unsigned short* ipwb = (unsigned short*)alloc(768 * 256 * 2);
    unsigned short* opwb = (unsigned short*)alloc(256 * 256 * 2);
    float* ipbs          = (float*)alloc(768 * 4);
    unsigned short* Hb   = (unsigned short*)alloc((size_t)N_NODES * 256 * 2);
    unsigned short* XAb  = (unsigned short*)alloc((size_t)N_NODES * 256 * 2);
    unsigned short* XBb  = (unsigned short*)alloc((size_t)N_NODES * 256 * 2);
    unsigned short* QKVb = (unsigned short*)alloc((size_t)N_NODES * 768 * 2);
    unsigned short* Vt   = (unsigned short*)alloc((size_t)4 * 64 * 4096 * 2);
    unsigned short* Po   = (unsigned short*)alloc((size_t)16 * 4096 * 64 * 2);
    float* Pl            = (float*)alloc((size_t)16 * 4096 * 4);

    const int* row = eix;
    const int* col = eix + N_EDGES;

    hipMemsetAsync(dinv, 0, N_NODES * 4, stream);
    hipMemsetAsync(cnt, 0, N_NODES * 4, stream);
    prep_all<<<512, 256, 0, stream>>>(x0, ipw, opw, ipb, W1, W2, W3,
                                      x0b, ipwb, opwb, ipbs, W1t, W2t, W3t);
    deg_accum<<<512, 256, 0, stream>>>(col, ew, dinv, cnt);
    scan_offsets<<<1, 1024, 0, stream>>>(cnt, dinv, off, fill);
    scatter_edges<<<512, 256, 0, stream>>>(row, col, ew, dinv, fill, ep);

    // GCN layer 1
    gemm_bf16<false, 0, false><<<dim3(4, 128), 64, 0, stream>>>(x0b, W1t, nullptr, Hb, nullptr, 256);
    gcn_agg<256, false><<<N_NODES, 64, 0, stream>>>(Hb, off, ep, dinv, b1, XAb, nullptr);
    // MHA 1 (+relu)
    gemm_bf16<true, 0, true><<<dim3(12, 128), 64, 0, stream>>>(XAb, ipwb, ipbs, QKVb, Vt, 768);
    attn_mfma<<<dim3(64, 4, 4), 256, 0, stream>>>(QKVb, Vt, Po, Pl);
    attn_combine<<<N_NODES / 4, 256, 0, stream>>>(Po, Pl, Hb);
    gemm_bf16<true, 1, false><<<dim3(4, 128), 64, 0, stream>>>(Hb, opwb, opb, XBb, nullptr, 256);
    // GCN layer 2
    gemm_bf16<false, 0, false><<<dim3(4, 128), 64, 0, stream>>>(XBb, W2t, nullptr, Hb, nullptr, 256);
    gcn_agg<256, false><<<N_NODES, 64, 0, stream>>>(Hb, off, ep, dinv, b2, XAb, nullptr);
    // MHA 2 (+relu)
    gemm_bf16<true, 0, true><<<dim3(12, 128), 64, 0, stream>>>(XAb, ipwb, ipbs, QKVb, Vt, 768);
    attn_mfma<<<dim3(64, 4, 4), 256, 0, stream>>>(QKVb, Vt, Po, Pl);
    attn_combine<<<N_NODES / 4, 256, 0, stream>>>(Po, Pl, Hb);
    gemm_bf16<true, 1, false><<<dim3(4, 128), 64, 0, stream>>>(Hb, opwb, opb, XBb, nullptr, 256);
    // GCN layer 3 (+sigmoid) -> d_out
    gemm_bf16<false, 0, false><<<dim3(2, 128), 64, 0, stream>>>(XBb, W3t, nullptr, Hb, nullptr, 128);
    gcn_agg<128, true><<<N_NODES, 64, 0, stream>>>(Hb, off, ep, dinv, b3, nullptr, out);
}